// Round 7
// baseline (275.913 us; speedup 1.0000x reference)
//
#include <hip/hip_runtime.h>

#define NN 100000
#define NE 1600000
#define NB 391        // node buckets: node >> 8 (256 nodes/bucket, last=160)
#define NBLK 391      // edge chunks of CHUNK
#define CHUNK 4096

// ---- bf16 helpers (RNE) ----------------------------------------------------
__device__ __forceinline__ float bflo(unsigned u) { return __uint_as_float(u << 16); }
__device__ __forceinline__ float bfhi(unsigned u) { return __uint_as_float(u & 0xffff0000u); }
__device__ __forceinline__ unsigned short f2bf(float f) {
    unsigned u = __float_as_uint(f);
    return (unsigned short)((u + 0x7fff + ((u >> 16) & 1)) >> 16);
}
__device__ __forceinline__ unsigned packbf(float a, float b) {
    return (unsigned)f2bf(a) | ((unsigned)f2bf(b) << 16);
}

// ---------------------------------------------------------------------------
// B1: per-(chunk,bucket) counts via LDS histograms (no global atomics).
// ---------------------------------------------------------------------------
__global__ __launch_bounds__(256) void k_bcount(const int* __restrict__ src,
                                                const int* __restrict__ dst,
                                                int* __restrict__ counts_d,
                                                int* __restrict__ counts_s) {
    __shared__ int hd[NB], hs[NB];
    int tid = threadIdx.x, blk = blockIdx.x;
    for (int i = tid; i < NB; i += 256) { hd[i] = 0; hs[i] = 0; }
    __syncthreads();
    int e0 = blk * CHUNK, ee = min(e0 + CHUNK, NE);
    for (int e = e0 + tid; e < ee; e += 256) {
        atomicAdd(&hd[dst[e] >> 8], 1);
        atomicAdd(&hs[src[e] >> 8], 1);
    }
    __syncthreads();
    for (int i = tid; i < NB; i += 256) {
        counts_d[blk * NB + i] = hd[i];
        counts_s[blk * NB + i] = hs[i];
    }
}

// ---------------------------------------------------------------------------
// B2: per-bucket exclusive scan over chunks (in place) + bucket totals.
// ---------------------------------------------------------------------------
__global__ __launch_bounds__(256) void k_scan(int* __restrict__ counts_d,
                                              int* __restrict__ counts_s,
                                              int* __restrict__ totd,
                                              int* __restrict__ tots) {
    int b = blockIdx.x;
    int* T; int* tot;
    if (b < NB) { T = counts_d; tot = totd; }
    else        { T = counts_s; tot = tots; b -= NB; }
    __shared__ int sd[256];
    int tid = threadIdx.x;
    int carry = 0;
    for (int base = 0; base < NBLK; base += 256) {
        int idx = base + tid;
        int v = (idx < NBLK) ? T[idx * NB + b] : 0;
        sd[tid] = v;
        __syncthreads();
        for (int off = 1; off < 256; off <<= 1) {
            int t = (tid >= off) ? sd[tid - off] : 0;
            __syncthreads();
            sd[tid] += t;
            __syncthreads();
        }
        if (idx < NBLK) T[idx * NB + b] = carry + sd[tid] - v;
        int bt = sd[255];
        __syncthreads();
        carry += bt;
    }
    if (tid == 0) tot[b] = carry;
}

// ---------------------------------------------------------------------------
// B3: exclusive scan of bucket totals -> bucket base (+ sentinel = NE).
// ---------------------------------------------------------------------------
__global__ __launch_bounds__(256) void k_scan2(const int* __restrict__ totd,
                                               int* __restrict__ based,
                                               const int* __restrict__ tots,
                                               int* __restrict__ bases) {
    const int* T = blockIdx.x ? tots : totd;
    int* B = blockIdx.x ? bases : based;
    __shared__ int sd[256];
    int tid = threadIdx.x;
    int carry = 0;
    for (int base = 0; base < NB; base += 256) {
        int idx = base + tid;
        int v = (idx < NB) ? T[idx] : 0;
        sd[tid] = v;
        __syncthreads();
        for (int off = 1; off < 256; off <<= 1) {
            int t = (tid >= off) ? sd[tid - off] : 0;
            __syncthreads();
            sd[tid] += t;
            __syncthreads();
        }
        if (idx < NB) B[idx] = carry + sd[tid] - v;
        int bt = sd[255];
        __syncthreads();
        carry += bt;
    }
    if (tid == 0) B[NB] = carry;   // == NE
}

// ---------------------------------------------------------------------------
// B4: scatter edges into bucketed lists with LDS cursors (no global atomics).
// ---------------------------------------------------------------------------
__global__ __launch_bounds__(256) void k_bscatter(
        const int* __restrict__ src, const int* __restrict__ dst,
        const int* __restrict__ counts_d, const int* __restrict__ counts_s,
        const int* __restrict__ based, const int* __restrict__ bases,
        unsigned* __restrict__ bkd, unsigned char* __restrict__ bks) {
    __shared__ int cud[NB], cus[NB];
    int tid = threadIdx.x, blk = blockIdx.x;
    for (int i = tid; i < NB; i += 256) {
        cud[i] = based[i] + counts_d[blk * NB + i];
        cus[i] = bases[i] + counts_s[blk * NB + i];
    }
    __syncthreads();
    int e0 = blk * CHUNK, ee = min(e0 + CHUNK, NE);
    for (int e = e0 + tid; e < ee; e += 256) {
        int s = src[e], d = dst[e];
        int p = atomicAdd(&cud[d >> 8], 1);
        bkd[p] = ((unsigned)(d & 255) << 17) | (unsigned)s;
        int q = atomicAdd(&cus[s >> 8], 1);
        bks[q] = (unsigned char)(s & 255);
    }
}

// ---------------------------------------------------------------------------
// B5: per-bucket pass: in-degree counts, CSR start, CSR scatter (all LDS).
// ---------------------------------------------------------------------------
__global__ __launch_bounds__(256) void k_p2d(const unsigned* __restrict__ bkd,
                                             const int* __restrict__ based,
                                             int* __restrict__ cd,
                                             int* __restrict__ start,
                                             int* __restrict__ csr_s) {
    __shared__ int hist[256], scn[256];
    int b = blockIdx.x, tid = threadIdx.x;
    hist[tid] = 0;
    __syncthreads();
    int eb = based[b], ee = based[b + 1];
    for (int e = eb + tid; e < ee; e += 256)
        atomicAdd(&hist[bkd[e] >> 17], 1);
    __syncthreads();
    int c = hist[tid];
    scn[tid] = c;
    __syncthreads();
    for (int off = 1; off < 256; off <<= 1) {
        int t = (tid >= off) ? scn[tid - off] : 0;
        __syncthreads();
        scn[tid] += t;
        __syncthreads();
    }
    int excl = scn[tid] - c;
    int node = (b << 8) + tid;
    if (node < NN) { cd[node] = c; start[node] = eb + excl; }
    hist[tid] = eb + excl;        // reuse as cursor
    __syncthreads();
    for (int e = eb + tid; e < ee; e += 256) {
        unsigned pk = bkd[e];
        int p = atomicAdd(&hist[pk >> 17], 1);
        csr_s[p] = (int)(pk & 0x1FFFFu);
    }
}

// ---------------------------------------------------------------------------
// B6: per-bucket out-degree counts from byte list.
// ---------------------------------------------------------------------------
__global__ __launch_bounds__(256) void k_p2s(const unsigned char* __restrict__ bks,
                                             const int* __restrict__ bases,
                                             int* __restrict__ cs) {
    __shared__ int hist[256];
    int b = blockIdx.x, tid = threadIdx.x;
    hist[tid] = 0;
    __syncthreads();
    int eb = bases[b], ee = bases[b + 1];
    for (int e = eb + tid; e < ee; e += 256)
        atomicAdd(&hist[bks[e]], 1);
    __syncthreads();
    int node = (b << 8) + tid;
    if (node < NN) cs[node] = hist[tid];
}

// ---------------------------------------------------------------------------
// K_norm: dis = outdeg>0 ? rsqrt(outdeg) : 0 ;  disg = rsqrt(indeg+1)
// ---------------------------------------------------------------------------
__global__ __launch_bounds__(256) void k_norm(const int* __restrict__ cs,
                                              const int* __restrict__ cd,
                                              float* __restrict__ dis,
                                              float* __restrict__ disg) {
    int i = blockIdx.x * 256 + threadIdx.x;
    if (i < NN) {
        int c = cs[i], d = cd[i];
        dis[i]  = c > 0 ? rsqrtf((float)c) : 0.0f;
        disg[i] = rsqrtf((float)d + 1.0f);
    }
}

// ---------------------------------------------------------------------------
// K_cvt: pre-scaled bf16 rows, FEATURE-SPLIT into two 3.2MB tables:
//   xs_lo[node][16] = bf16(dis*x[:,0:16]),  xs_hi = features 16..31
// ---------------------------------------------------------------------------
__global__ __launch_bounds__(256) void k_cvt(const float* __restrict__ x,
                                             const float* __restrict__ dis,
                                             unsigned short* __restrict__ xs_lo,
                                             unsigned short* __restrict__ xs_hi) {
    int i = blockIdx.x * 256 + threadIdx.x;
    if (i < NN * 32) {
        int node = i >> 5, f = i & 31;
        unsigned short v = f2bf(x[i] * dis[node]);
        if (f < 16) xs_lo[node * 16 + f] = v;
        else        xs_hi[node * 16 + (f - 16)] = v;
    }
}

// ---------------------------------------------------------------------------
// K_gath_lx: one feature-half gather pass (table = 3.2MB, L2/XCD-resident).
//   Lx2[node*16 + hofs + c8] = -dis[node] * sum_e xs_h[src_e][c8]  (float2)
// 32-lane group per node; 8 lanes/edge (c8 = uint col), 4 edge slots (sub),
// 4-deep batching -> 16 x 32B rows in flight per group.
// ---------------------------------------------------------------------------
__global__ __launch_bounds__(256) void k_gath_lx(const unsigned* __restrict__ xsh,
                                                 const int* __restrict__ csr_s,
                                                 const int* __restrict__ start,
                                                 const int* __restrict__ cd,
                                                 const float* __restrict__ dis,
                                                 float2* __restrict__ Lx2,
                                                 int hofs) {
    int tid = threadIdx.x;
    int node = blockIdx.x * 8 + (tid >> 5);
    int lane = tid & 31, sub = (lane >> 3) & 3, c8 = lane & 7;
    int st = start[node], cn = cd[node];

    float accx = 0.0f, accy = 0.0f;
    for (int j = 0; j < cn; j += 16) {
        int s[4]; float m[4];
#pragma unroll
        for (int u = 0; u < 4; ++u) {
            int jj = j + 4 * u + sub;
            int jc = jj < cn ? jj : cn - 1;
            s[u] = csr_s[st + jc];
            m[u] = jj < cn ? 1.0f : 0.0f;
        }
        unsigned v[4];
#pragma unroll
        for (int u = 0; u < 4; ++u) v[u] = xsh[s[u] * 8 + c8];
#pragma unroll
        for (int u = 0; u < 4; ++u) {
            accx = fmaf(m[u], bflo(v[u]), accx);
            accy = fmaf(m[u], bfhi(v[u]), accy);
        }
    }
    accx += __shfl_xor(accx, 8, 32);  accx += __shfl_xor(accx, 16, 32);
    accy += __shfl_xor(accy, 8, 32);  accy += __shfl_xor(accy, 16, 32);
    if (lane < 8) {
        float w = -dis[node];
        Lx2[node * 16 + hofs + lane] = make_float2(w * accx, w * accy);
    }
}

// ---------------------------------------------------------------------------
// K_dense: GRU-gate GEMMs + GCN weight GEMM (shuffle-GEMM, weights in LDS).
// Reads Lx (f32), writes hws feature-split bf16 tables.
// ---------------------------------------------------------------------------
__global__ __launch_bounds__(256) void k_dense(
        const float* __restrict__ x, const float* __restrict__ Lxf,
        const float* __restrict__ W_xz, const float* __restrict__ b_xz,
        const float* __restrict__ b_hz,
        const float* __restrict__ W_xh, const float* __restrict__ b_xh,
        const float* __restrict__ b_hh,
        const float* __restrict__ W_gcn, const float* __restrict__ disg,
        unsigned* __restrict__ hws_lo, unsigned* __restrict__ hws_hi) {
    __shared__ float sW[5 * 1024];   // Wz0,Wz1,Wh0,Wh1,Wgcn  (k-major: [k][f])
    __shared__ float sbz[32], sbh[32];
    int tid = threadIdx.x;
    for (int i = tid; i < 2048; i += 256) { sW[i] = W_xz[i]; sW[2048 + i] = W_xh[i]; }
    for (int i = tid; i < 1024; i += 256) { sW[4096 + i] = W_gcn[i]; }
    if (tid < 32) { sbz[tid] = b_xz[tid] + b_hz[tid]; sbh[tid] = b_xh[tid] + b_hh[tid]; }
    __syncthreads();

    int node = blockIdx.x * 8 + (tid >> 5);
    int lane = tid & 31;
    const float* Wz0 = sW;
    const float* Wz1 = sW + 1024;
    const float* Wh0 = sW + 2048;
    const float* Wh1 = sW + 3072;
    const float* Wg  = sW + 4096;

    float xv = x[node * 32 + lane];
    float lv = Lxf[node * 32 + lane];
    float z = sbz[lane], t = sbh[lane];
#pragma unroll
    for (int k = 0; k < 32; ++k) {
        float xk = __shfl(xv, k, 32);
        float lk = __shfl(lv, k, 32);
        z = fmaf(xk, Wz0[k * 32 + lane], z);
        z = fmaf(lk, Wz1[k * 32 + lane], z);
        t = fmaf(xk, Wh0[k * 32 + lane], t);
        t = fmaf(lk, Wh1[k * 32 + lane], t);
    }
    float Z = 1.0f / (1.0f + expf(-z));
    float H = (1.0f - Z) * tanhf(t);

    float hwv = 0.0f;
#pragma unroll
    for (int k = 0; k < 32; ++k) {
        float Hk = __shfl(H, k, 32);
        hwv = fmaf(Hk, Wg[k * 32 + lane], hwv);
    }
    float dgh = disg[node] * hwv;                 // pre-scale by disg[node]
    int idx = lane & 7;
    int base = (lane & 8) ? 16 : 0;
    float h0 = __shfl(dgh, base + 2 * idx, 32);
    float h1 = __shfl(dgh, base + 2 * idx + 1, 32);
    if (lane < 8)       hws_lo[node * 8 + idx] = packbf(h0, h1);
    else if (lane < 16) hws_hi[node * 8 + idx] = packbf(h0, h1);
}

// ---------------------------------------------------------------------------
// K_gath_h: GCN gather pass for one feature-half + self-loop, writes h (f32).
//   h2[node*16+hofs+c8] = disg[node] * (sum_e hws_h[src_e][c8] + hws_h[node][c8])
// ---------------------------------------------------------------------------
__global__ __launch_bounds__(256) void k_gath_h(const unsigned* __restrict__ hwsh,
                                                const int* __restrict__ csr_s,
                                                const int* __restrict__ start,
                                                const int* __restrict__ cd,
                                                const float* __restrict__ disg,
                                                float2* __restrict__ h2,
                                                int hofs) {
    int tid = threadIdx.x;
    int node = blockIdx.x * 8 + (tid >> 5);
    int lane = tid & 31, sub = (lane >> 3) & 3, c8 = lane & 7;
    int st = start[node], cn = cd[node];

    float accx = 0.0f, accy = 0.0f;
    for (int j = 0; j < cn; j += 16) {
        int s[4]; float m[4];
#pragma unroll
        for (int u = 0; u < 4; ++u) {
            int jj = j + 4 * u + sub;
            int jc = jj < cn ? jj : cn - 1;
            s[u] = csr_s[st + jc];
            m[u] = jj < cn ? 1.0f : 0.0f;
        }
        unsigned v[4];
#pragma unroll
        for (int u = 0; u < 4; ++u) v[u] = hwsh[s[u] * 8 + c8];
#pragma unroll
        for (int u = 0; u < 4; ++u) {
            accx = fmaf(m[u], bflo(v[u]), accx);
            accy = fmaf(m[u], bfhi(v[u]), accy);
        }
    }
    accx += __shfl_xor(accx, 8, 32);  accx += __shfl_xor(accx, 16, 32);
    accy += __shfl_xor(accy, 8, 32);  accy += __shfl_xor(accy, 16, 32);
    if (lane < 8) {
        unsigned su = hwsh[node * 8 + lane];     // self row (pre-scaled by disg)
        float dg = disg[node];
        h2[node * 16 + hofs + lane] = make_float2(dg * (accx + bflo(su)),
                                                  dg * (accy + bfhi(su)));
    }
}

// ---------------------------------------------------------------------------
// K_fin: out[node] = relu(h + b_gcn) . W_lin + b_lin
// ---------------------------------------------------------------------------
__global__ __launch_bounds__(256) void k_fin(const float* __restrict__ hh,
                                             const float* __restrict__ b_gcn,
                                             const float* __restrict__ W_lin,
                                             const float* __restrict__ b_lin,
                                             float* __restrict__ out) {
    int tid = threadIdx.x;
    int node = blockIdx.x * 8 + (tid >> 5);
    int lane = tid & 31;
    float v = fmaxf(hh[node * 32 + lane] + b_gcn[lane], 0.0f) * W_lin[lane];
#pragma unroll
    for (int o = 16; o > 0; o >>= 1) v += __shfl_xor(v, o, 32);
    if (lane == 0) out[node] = v + b_lin[0];
}

extern "C" void kernel_launch(void* const* d_in, const int* in_sizes, int n_in,
                              void* d_out, int out_size, void* d_ws, size_t ws_size,
                              hipStream_t stream) {
    const float* x     = (const float*)d_in[0];
    const int*   ei    = (const int*)d_in[1];
    const int*   src   = ei;
    const int*   dst   = ei + NE;
    const float* W_xz  = (const float*)d_in[2];
    const float* b_xz  = (const float*)d_in[3];
    const float* b_hz  = (const float*)d_in[5];
    // W_xr/b_xr/W_hr/b_hr (d_in[6..9]) are dead: R only multiplies H0 == 0.
    const float* W_xh  = (const float*)d_in[10];
    const float* b_xh  = (const float*)d_in[11];
    const float* b_hh  = (const float*)d_in[13];
    const float* W_gcn = (const float*)d_in[14];
    const float* b_gcn = (const float*)d_in[15];
    const float* W_lin = (const float*)d_in[16];
    const float* b_lin = (const float*)d_in[17];
    float* out = (float*)d_out;

    // Workspace (4B words). Every array fully written before read (no memsets).
    // Aliases: xs_lo/xs_hi overlay bkd/bks (dead after k_p2d/k_p2s);
    //          h overlays Lx (dead after k_dense).
    int* w = (int*)d_ws;
    int* counts_d = w;                    w += 160000;          // NBLK*NB=152881
    int* counts_s = w;                    w += 160000;
    int* totd     = w;                    w += 512;
    int* tots     = w;                    w += 512;
    int* based    = w;                    w += 512;             // NB+1
    int* bases    = w;                    w += 512;
    int* cs       = w;                    w += NN;
    int* cd       = w;                    w += NN;
    int* start    = w;                    w += NN;
    float* dis    = (float*)w;            w += NN;
    float* disg   = (float*)w;            w += NN;
    unsigned* hws_lo = (unsigned*)w;      w += 8 * NN;          // bf16-pair table
    unsigned* hws_hi = (unsigned*)w;      w += 8 * NN;
    float*    Lxf    = (float*)w;         w += 32 * NN;         // f32; h aliases
    unsigned* bkd    = (unsigned*)w;      w += NE;              // packed dst list
    unsigned char* bks = (unsigned char*)w; w += NE / 4;        // byte src list
    int* csr_s    = w;                    w += NE;
    unsigned* xs_lo = bkd;                                      // alias (8N each)
    unsigned* xs_hi = bkd + 8 * NN;
    float*    hh    = Lxf;                                      // alias
    float2*   Lx2   = (float2*)Lxf;
    float2*   h2    = (float2*)hh;

    k_bcount  <<<NBLK, 256, 0, stream>>>(src, dst, counts_d, counts_s);
    k_scan    <<<2 * NB, 256, 0, stream>>>(counts_d, counts_s, totd, tots);
    k_scan2   <<<2, 256, 0, stream>>>(totd, based, tots, bases);
    k_bscatter<<<NBLK, 256, 0, stream>>>(src, dst, counts_d, counts_s,
                                         based, bases, bkd, bks);
    k_p2d     <<<NB, 256, 0, stream>>>(bkd, based, cd, start, csr_s);
    k_p2s     <<<NB, 256, 0, stream>>>(bks, bases, cs);
    k_norm    <<<(NN + 255) / 256, 256, 0, stream>>>(cs, cd, dis, disg);
    k_cvt     <<<(NN * 32 + 255) / 256, 256, 0, stream>>>(x, dis,
                                          (unsigned short*)xs_lo,
                                          (unsigned short*)xs_hi);
    k_gath_lx <<<NN / 8, 256, 0, stream>>>(xs_lo, csr_s, start, cd, dis, Lx2, 0);
    k_gath_lx <<<NN / 8, 256, 0, stream>>>(xs_hi, csr_s, start, cd, dis, Lx2, 8);
    k_dense   <<<NN / 8, 256, 0, stream>>>(x, Lxf, W_xz, b_xz, b_hz,
                                           W_xh, b_xh, b_hh, W_gcn, disg,
                                           hws_lo, hws_hi);
    k_gath_h  <<<NN / 8, 256, 0, stream>>>(hws_lo, csr_s, start, cd, disg, h2, 0);
    k_gath_h  <<<NN / 8, 256, 0, stream>>>(hws_hi, csr_s, start, cd, disg, h2, 8);
    k_fin     <<<NN / 8, 256, 0, stream>>>(hh, b_gcn, W_lin, b_lin, out);
}

// Round 8
// 196.146 us; speedup vs baseline: 1.4067x; 1.4067x over previous
//
#include <hip/hip_runtime.h>
#include <hip/hip_fp16.h>

#define NN 100000
#define NE 1600000
#define NB 391        // node buckets: node >> 8 (256 nodes/bucket, last=160)
#define NBLK 391      // edge chunks of CHUNK
#define CHUNK 4096

// ---- fp16 helpers ----------------------------------------------------------
__device__ __forceinline__ float h16lo(unsigned u) {
    return __half2float(__ushort_as_half((unsigned short)(u & 0xffffu)));
}
__device__ __forceinline__ float h16hi(unsigned u) {
    return __half2float(__ushort_as_half((unsigned short)(u >> 16)));
}
__device__ __forceinline__ unsigned short h16(float f) {
    return __half_as_ushort(__float2half(f));
}
__device__ __forceinline__ unsigned pack2h(float a, float b) {
    return (unsigned)h16(a) | ((unsigned)h16(b) << 16);
}

using f16x8  = __attribute__((ext_vector_type(8)))  _Float16;
using f32x16 = __attribute__((ext_vector_type(16))) float;

// ---------------------------------------------------------------------------
// B1: per-(chunk,bucket) counts via LDS histograms (no global atomics).
// ---------------------------------------------------------------------------
__global__ __launch_bounds__(256) void k_bcount(const int* __restrict__ src,
                                                const int* __restrict__ dst,
                                                int* __restrict__ counts_d,
                                                int* __restrict__ counts_s) {
    __shared__ int hd[NB], hs[NB];
    int tid = threadIdx.x, blk = blockIdx.x;
    for (int i = tid; i < NB; i += 256) { hd[i] = 0; hs[i] = 0; }
    __syncthreads();
    int e0 = blk * CHUNK, ee = min(e0 + CHUNK, NE);
    for (int e = e0 + tid; e < ee; e += 256) {
        atomicAdd(&hd[dst[e] >> 8], 1);
        atomicAdd(&hs[src[e] >> 8], 1);
    }
    __syncthreads();
    for (int i = tid; i < NB; i += 256) {
        counts_d[blk * NB + i] = hd[i];
        counts_s[blk * NB + i] = hs[i];
    }
}

// ---------------------------------------------------------------------------
// B2: per-bucket exclusive scan over chunks (in place) + bucket totals.
// ---------------------------------------------------------------------------
__global__ __launch_bounds__(256) void k_scan(int* __restrict__ counts_d,
                                              int* __restrict__ counts_s,
                                              int* __restrict__ totd,
                                              int* __restrict__ tots) {
    int b = blockIdx.x;
    int* T; int* tot;
    if (b < NB) { T = counts_d; tot = totd; }
    else        { T = counts_s; tot = tots; b -= NB; }
    __shared__ int sd[256];
    int tid = threadIdx.x;
    int carry = 0;
    for (int base = 0; base < NBLK; base += 256) {
        int idx = base + tid;
        int v = (idx < NBLK) ? T[idx * NB + b] : 0;
        sd[tid] = v;
        __syncthreads();
        for (int off = 1; off < 256; off <<= 1) {
            int t = (tid >= off) ? sd[tid - off] : 0;
            __syncthreads();
            sd[tid] += t;
            __syncthreads();
        }
        if (idx < NBLK) T[idx * NB + b] = carry + sd[tid] - v;
        int bt = sd[255];
        __syncthreads();
        carry += bt;
    }
    if (tid == 0) tot[b] = carry;
}

// ---------------------------------------------------------------------------
// B3: exclusive scan of bucket totals -> bucket base (+ sentinel = NE).
// ---------------------------------------------------------------------------
__global__ __launch_bounds__(256) void k_scan2(const int* __restrict__ totd,
                                               int* __restrict__ based,
                                               const int* __restrict__ tots,
                                               int* __restrict__ bases) {
    const int* T = blockIdx.x ? tots : totd;
    int* B = blockIdx.x ? bases : based;
    __shared__ int sd[256];
    int tid = threadIdx.x;
    int carry = 0;
    for (int base = 0; base < NB; base += 256) {
        int idx = base + tid;
        int v = (idx < NB) ? T[idx] : 0;
        sd[tid] = v;
        __syncthreads();
        for (int off = 1; off < 256; off <<= 1) {
            int t = (tid >= off) ? sd[tid - off] : 0;
            __syncthreads();
            sd[tid] += t;
            __syncthreads();
        }
        if (idx < NB) B[idx] = carry + sd[tid] - v;
        int bt = sd[255];
        __syncthreads();
        carry += bt;
    }
    if (tid == 0) B[NB] = carry;   // == NE
}

// ---------------------------------------------------------------------------
// B4: scatter edges into bucketed lists with LDS cursors (no global atomics).
// ---------------------------------------------------------------------------
__global__ __launch_bounds__(256) void k_bscatter(
        const int* __restrict__ src, const int* __restrict__ dst,
        const int* __restrict__ counts_d, const int* __restrict__ counts_s,
        const int* __restrict__ based, const int* __restrict__ bases,
        unsigned* __restrict__ bkd, unsigned char* __restrict__ bks) {
    __shared__ int cud[NB], cus[NB];
    int tid = threadIdx.x, blk = blockIdx.x;
    for (int i = tid; i < NB; i += 256) {
        cud[i] = based[i] + counts_d[blk * NB + i];
        cus[i] = bases[i] + counts_s[blk * NB + i];
    }
    __syncthreads();
    int e0 = blk * CHUNK, ee = min(e0 + CHUNK, NE);
    for (int e = e0 + tid; e < ee; e += 256) {
        int s = src[e], d = dst[e];
        int p = atomicAdd(&cud[d >> 8], 1);
        bkd[p] = ((unsigned)(d & 255) << 17) | (unsigned)s;
        int q = atomicAdd(&cus[s >> 8], 1);
        bks[q] = (unsigned char)(s & 255);
    }
}

// ---------------------------------------------------------------------------
// B5: per-bucket pass: in-degree counts, CSR start, CSR scatter (all LDS).
// ---------------------------------------------------------------------------
__global__ __launch_bounds__(256) void k_p2d(const unsigned* __restrict__ bkd,
                                             const int* __restrict__ based,
                                             int* __restrict__ cd,
                                             int* __restrict__ start,
                                             int* __restrict__ csr_s) {
    __shared__ int hist[256], scn[256];
    int b = blockIdx.x, tid = threadIdx.x;
    hist[tid] = 0;
    __syncthreads();
    int eb = based[b], ee = based[b + 1];
    for (int e = eb + tid; e < ee; e += 256)
        atomicAdd(&hist[bkd[e] >> 17], 1);
    __syncthreads();
    int c = hist[tid];
    scn[tid] = c;
    __syncthreads();
    for (int off = 1; off < 256; off <<= 1) {
        int t = (tid >= off) ? scn[tid - off] : 0;
        __syncthreads();
        scn[tid] += t;
        __syncthreads();
    }
    int excl = scn[tid] - c;
    int node = (b << 8) + tid;
    if (node < NN) { cd[node] = c; start[node] = eb + excl; }
    hist[tid] = eb + excl;        // reuse as cursor
    __syncthreads();
    for (int e = eb + tid; e < ee; e += 256) {
        unsigned pk = bkd[e];
        int p = atomicAdd(&hist[pk >> 17], 1);
        csr_s[p] = (int)(pk & 0x1FFFFu);
    }
}

// ---------------------------------------------------------------------------
// B6: per-bucket out-degree counts from byte list.
// ---------------------------------------------------------------------------
__global__ __launch_bounds__(256) void k_p2s(const unsigned char* __restrict__ bks,
                                             const int* __restrict__ bases,
                                             int* __restrict__ cs) {
    __shared__ int hist[256];
    int b = blockIdx.x, tid = threadIdx.x;
    hist[tid] = 0;
    __syncthreads();
    int eb = bases[b], ee = bases[b + 1];
    for (int e = eb + tid; e < ee; e += 256)
        atomicAdd(&hist[bks[e]], 1);
    __syncthreads();
    int node = (b << 8) + tid;
    if (node < NN) cs[node] = hist[tid];
}

// ---------------------------------------------------------------------------
// K_norm: dis = outdeg>0 ? rsqrt(outdeg) : 0 ;  disg = rsqrt(indeg+1)
// ---------------------------------------------------------------------------
__global__ __launch_bounds__(256) void k_norm(const int* __restrict__ cs,
                                              const int* __restrict__ cd,
                                              float* __restrict__ dis,
                                              float* __restrict__ disg) {
    int i = blockIdx.x * 256 + threadIdx.x;
    if (i < NN) {
        int c = cs[i], d = cd[i];
        dis[i]  = c > 0 ? rsqrtf((float)c) : 0.0f;
        disg[i] = rsqrtf((float)d + 1.0f);
    }
}

// ---------------------------------------------------------------------------
// K_cvt: fp16 tables.
//   xs_lo/xs_hi: SCALED gather tables (dis[s]*x), feature-split 16+16.
//   ALu: combined A-operand rows [x row fp16 (k=0..31) | Lx row (k=32..63)];
//        x half written here, Lx half written by k_gath_lx.
// ---------------------------------------------------------------------------
__global__ __launch_bounds__(256) void k_cvt(const float* __restrict__ x,
                                             const float* __restrict__ dis,
                                             unsigned short* __restrict__ xs_lo,
                                             unsigned short* __restrict__ xs_hi,
                                             unsigned short* __restrict__ ALu) {
    int i = blockIdx.x * 256 + threadIdx.x;
    if (i < NN * 32) {
        int node = i >> 5, f = i & 31;
        float xv = x[i];
        ALu[node * 64 + f] = h16(xv);
        unsigned short hs = h16(xv * dis[node]);
        if (f < 16) xs_lo[node * 16 + f] = hs;
        else        xs_hi[node * 16 + (f - 16)] = hs;
    }
}

// ---------------------------------------------------------------------------
// K_wcvt: fp16 TRANSPOSED weight tables (B-fragment friendly: row f, k contig)
//   BzT[f][k64] = [Wz0;Wz1]^T,  BhT[f][k64] = [Wh0;Wh1]^T,  WgT[f][k32]
// ---------------------------------------------------------------------------
__global__ __launch_bounds__(256) void k_wcvt(const float* __restrict__ W_xz,
                                              const float* __restrict__ W_xh,
                                              const float* __restrict__ W_gcn,
                                              unsigned short* __restrict__ BzT,
                                              unsigned short* __restrict__ BhT,
                                              unsigned short* __restrict__ WgT) {
    int tid = threadIdx.x;
    for (int idx = tid; idx < 2048; idx += 256) {
        int f = idx >> 6, k = idx & 63;
        float vz = (k < 32) ? W_xz[k * 32 + f] : W_xz[1024 + (k - 32) * 32 + f];
        float vh = (k < 32) ? W_xh[k * 32 + f] : W_xh[1024 + (k - 32) * 32 + f];
        BzT[idx] = h16(vz);
        BhT[idx] = h16(vh);
    }
    for (int idx = tid; idx < 1024; idx += 256) {
        int f = idx >> 5, k = idx & 31;
        WgT[idx] = h16(W_gcn[k * 32 + f]);
    }
}

// ---------------------------------------------------------------------------
// K_gath_lx: one feature-half gather (table 3.2MB, L2-resident), fp16.
// Writes Lx half-row into the AL table (k=32..63 section), pre-multiplied by
// -dis[dst] (the dst factor of lap_w hoists out of the sum).
// ---------------------------------------------------------------------------
__global__ __launch_bounds__(256) void k_gath_lx(const unsigned* __restrict__ xsh,
                                                 const int* __restrict__ csr_s,
                                                 const int* __restrict__ start,
                                                 const int* __restrict__ cd,
                                                 const float* __restrict__ dis,
                                                 unsigned* __restrict__ ALw,
                                                 int hofs) {
    int tid = threadIdx.x;
    int node = blockIdx.x * 8 + (tid >> 5);
    int lane = tid & 31, sub = (lane >> 3) & 3, c8 = lane & 7;
    int st = start[node], cn = cd[node];

    float accx = 0.0f, accy = 0.0f;
    for (int j = 0; j < cn; j += 16) {
        int s[4]; float m[4];
#pragma unroll
        for (int u = 0; u < 4; ++u) {
            int jj = j + 4 * u + sub;
            int jc = jj < cn ? jj : cn - 1;
            s[u] = csr_s[st + jc];
            m[u] = jj < cn ? 1.0f : 0.0f;
        }
        unsigned v[4];
#pragma unroll
        for (int u = 0; u < 4; ++u) v[u] = xsh[s[u] * 8 + c8];
#pragma unroll
        for (int u = 0; u < 4; ++u) {
            accx = fmaf(m[u], h16lo(v[u]), accx);
            accy = fmaf(m[u], h16hi(v[u]), accy);
        }
    }
    accx += __shfl_xor(accx, 8, 32);  accx += __shfl_xor(accx, 16, 32);
    accy += __shfl_xor(accy, 8, 32);  accy += __shfl_xor(accy, 16, 32);
    if (lane < 8) {
        float w = -dis[node];
        ALw[node * 32 + 16 + hofs + lane] = pack2h(w * accx, w * accy);
    }
}

// ---------------------------------------------------------------------------
// K_dmm: MFMA dense phase.  Per wave: 32-node tile.
//   [z|t] = AL(32x64) @ [BzT|BhT]  (8x mfma_f32_32x32x16_f16, 2 accumulators)
//   H = (1-sigmoid(z+bz))*tanh(t+bh)   (C-layout elementwise)
//   hw = H @ Wg  (transpose H via wave-private padded LDS tile, 2x MFMA)
//   hws tables = fp16(disg * hw)
// C/D layout (m74/m101): col=lane&31, row=(reg&3)+8*(reg>>2)+4*(lane>>5).
// A/B frag: row/col=lane&31, k = (lane>>5)*8 + e (8 k-contiguous fp16).
// ---------------------------------------------------------------------------
__global__ __launch_bounds__(256) void k_dmm(
        const f16x8* __restrict__ AL,     // [node*8 + c*2 + hi]
        const f16x8* __restrict__ BzT,    // [f*8 + c*2 + hi]
        const f16x8* __restrict__ BhT,
        const f16x8* __restrict__ WgT,    // [f*4 + c*2 + hi]
        const float* __restrict__ b_xz, const float* __restrict__ b_hz,
        const float* __restrict__ b_xh, const float* __restrict__ b_hh,
        const float* __restrict__ disg,
        unsigned short* __restrict__ hws_lo,
        unsigned short* __restrict__ hws_hi) {
    __shared__ unsigned short Hl[4 * 1280];   // per-wave 32 rows x 40 u16 (80B pad)
    int tid = threadIdx.x;
    int wv = blockIdx.x * 4 + (tid >> 6);
    if (wv > 3124) wv = 3124;                 // dup tail wave: same writes, safe
    int l = tid & 63, mrow = l & 31, hi = l >> 5;
    int n0 = wv * 32;
    unsigned short* Hw = Hl + (tid >> 6) * 1280;

    f32x16 accz = {}, acct = {};
    const f16x8* Arow = AL + (n0 + mrow) * 8 + hi;
#pragma unroll
    for (int c = 0; c < 4; ++c) {
        f16x8 a = Arow[c * 2];
        accz = __builtin_amdgcn_mfma_f32_32x32x16_f16(a, BzT[mrow * 8 + c * 2 + hi], accz, 0, 0, 0);
        acct = __builtin_amdgcn_mfma_f32_32x32x16_f16(a, BhT[mrow * 8 + c * 2 + hi], acct, 0, 0, 0);
    }
    float bz = b_xz[mrow] + b_hz[mrow];
    float bh = b_xh[mrow] + b_hh[mrow];
#pragma unroll
    for (int j = 0; j < 16; ++j) {
        float z = accz[j] + bz, t = acct[j] + bh;
        float Z = 1.0f / (1.0f + expf(-z));
        float H = (1.0f - Z) * tanhf(t);
        int r = (j & 3) + 8 * (j >> 2) + 4 * hi;
        Hw[r * 40 + mrow] = h16(H);          // H^T staging (row=node, col=f)
    }
    // same-wave LDS RAW: compiler inserts lgkmcnt wait before dependent reads
    f32x16 acch = {};
#pragma unroll
    for (int c = 0; c < 2; ++c) {
        f16x8 hfrag = *reinterpret_cast<const f16x8*>(&Hw[mrow * 40 + c * 16 + hi * 8]);
        acch = __builtin_amdgcn_mfma_f32_32x32x16_f16(hfrag, WgT[mrow * 4 + c * 2 + hi], acch, 0, 0, 0);
    }
#pragma unroll
    for (int j = 0; j < 16; ++j) {
        int r = (j & 3) + 8 * (j >> 2) + 4 * hi;
        int node = n0 + r;
        unsigned short hv = h16(disg[node] * acch[j]);
        if (mrow < 16) hws_lo[node * 16 + mrow] = hv;
        else           hws_hi[node * 16 + (mrow - 16)] = hv;
    }
}

// ---------------------------------------------------------------------------
// K_gath_h: GCN gather for one feature-half + self-loop, writes h (f32).
// ---------------------------------------------------------------------------
__global__ __launch_bounds__(256) void k_gath_h(const unsigned* __restrict__ hwsh,
                                                const int* __restrict__ csr_s,
                                                const int* __restrict__ start,
                                                const int* __restrict__ cd,
                                                const float* __restrict__ disg,
                                                float2* __restrict__ h2,
                                                int hofs) {
    int tid = threadIdx.x;
    int node = blockIdx.x * 8 + (tid >> 5);
    int lane = tid & 31, sub = (lane >> 3) & 3, c8 = lane & 7;
    int st = start[node], cn = cd[node];

    float accx = 0.0f, accy = 0.0f;
    for (int j = 0; j < cn; j += 16) {
        int s[4]; float m[4];
#pragma unroll
        for (int u = 0; u < 4; ++u) {
            int jj = j + 4 * u + sub;
            int jc = jj < cn ? jj : cn - 1;
            s[u] = csr_s[st + jc];
            m[u] = jj < cn ? 1.0f : 0.0f;
        }
        unsigned v[4];
#pragma unroll
        for (int u = 0; u < 4; ++u) v[u] = hwsh[s[u] * 8 + c8];
#pragma unroll
        for (int u = 0; u < 4; ++u) {
            accx = fmaf(m[u], h16lo(v[u]), accx);
            accy = fmaf(m[u], h16hi(v[u]), accy);
        }
    }
    accx += __shfl_xor(accx, 8, 32);  accx += __shfl_xor(accx, 16, 32);
    accy += __shfl_xor(accy, 8, 32);  accy += __shfl_xor(accy, 16, 32);
    if (lane < 8) {
        unsigned su = hwsh[node * 8 + lane];     // self row (pre-scaled by disg)
        float dg = disg[node];
        h2[node * 16 + hofs + lane] = make_float2(dg * (accx + h16lo(su)),
                                                  dg * (accy + h16hi(su)));
    }
}

// ---------------------------------------------------------------------------
// K_fin: out[node] = relu(h + b_gcn) . W_lin + b_lin
// ---------------------------------------------------------------------------
__global__ __launch_bounds__(256) void k_fin(const float* __restrict__ hh,
                                             const float* __restrict__ b_gcn,
                                             const float* __restrict__ W_lin,
                                             const float* __restrict__ b_lin,
                                             float* __restrict__ out) {
    int tid = threadIdx.x;
    int node = blockIdx.x * 8 + (tid >> 5);
    int lane = tid & 31;
    float v = fmaxf(hh[node * 32 + lane] + b_gcn[lane], 0.0f) * W_lin[lane];
#pragma unroll
    for (int o = 16; o > 0; o >>= 1) v += __shfl_xor(v, o, 32);
    if (lane == 0) out[node] = v + b_lin[0];
}

extern "C" void kernel_launch(void* const* d_in, const int* in_sizes, int n_in,
                              void* d_out, int out_size, void* d_ws, size_t ws_size,
                              hipStream_t stream) {
    const float* x     = (const float*)d_in[0];
    const int*   ei    = (const int*)d_in[1];
    const int*   src   = ei;
    const int*   dst   = ei + NE;
    const float* W_xz  = (const float*)d_in[2];
    const float* b_xz  = (const float*)d_in[3];
    const float* b_hz  = (const float*)d_in[5];
    // W_xr/b_xr/W_hr/b_hr (d_in[6..9]) are dead: R only multiplies H0 == 0.
    const float* W_xh  = (const float*)d_in[10];
    const float* b_xh  = (const float*)d_in[11];
    const float* b_hh  = (const float*)d_in[13];
    const float* W_gcn = (const float*)d_in[14];
    const float* b_gcn = (const float*)d_in[15];
    const float* W_lin = (const float*)d_in[16];
    const float* b_lin = (const float*)d_in[17];
    float* out = (float*)d_out;

    // Workspace (4B words). Every array fully written before read (no memsets).
    // Aliases: xs_lo/xs_hi overlay bkd (dead after k_p2d); h overlays AL
    // (dead after k_dmm).
    int* w = (int*)d_ws;
    int* counts_d = w;                    w += 160000;          // NBLK*NB=152881
    int* counts_s = w;                    w += 160000;
    int* totd     = w;                    w += 512;
    int* tots     = w;                    w += 512;
    int* based    = w;                    w += 512;             // NB+1
    int* bases    = w;                    w += 512;
    int* cs       = w;                    w += NN;
    int* cd       = w;                    w += NN;
    int* start    = w;                    w += NN;
    float* dis    = (float*)w;            w += NN;
    float* disg   = (float*)w;            w += NN;
    unsigned* hws_lo = (unsigned*)w;      w += 8 * NN;          // fp16 tables
    unsigned* hws_hi = (unsigned*)w;      w += 8 * NN;
    unsigned* ALw    = (unsigned*)w;      w += 32 * NN;         // [x|Lx] fp16 rows; h aliases
    unsigned* bkd    = (unsigned*)w;      w += NE;              // packed dst list
    unsigned char* bks = (unsigned char*)w; w += NE / 4;        // byte src list
    int* csr_s    = w;                    w += NE;
    unsigned short* BzT = (unsigned short*)w; w += 1024;        // 32f x 64k fp16
    unsigned short* BhT = (unsigned short*)w; w += 1024;
    unsigned short* WgT = (unsigned short*)w; w += 512;         // 32f x 32k fp16
    unsigned* xs_lo = bkd;                                      // alias (8N each)
    unsigned* xs_hi = bkd + 8 * NN;
    float*    hh    = (float*)ALw;                              // alias
    float2*   h2    = (float2*)hh;

    k_bcount  <<<NBLK, 256, 0, stream>>>(src, dst, counts_d, counts_s);
    k_scan    <<<2 * NB, 256, 0, stream>>>(counts_d, counts_s, totd, tots);
    k_scan2   <<<2, 256, 0, stream>>>(totd, based, tots, bases);
    k_bscatter<<<NBLK, 256, 0, stream>>>(src, dst, counts_d, counts_s,
                                         based, bases, bkd, bks);
    k_p2d     <<<NB, 256, 0, stream>>>(bkd, based, cd, start, csr_s);
    k_p2s     <<<NB, 256, 0, stream>>>(bks, bases, cs);
    k_norm    <<<(NN + 255) / 256, 256, 0, stream>>>(cs, cd, dis, disg);
    k_wcvt    <<<1, 256, 0, stream>>>(W_xz, W_xh, W_gcn, BzT, BhT, WgT);
    k_cvt     <<<(NN * 32 + 255) / 256, 256, 0, stream>>>(x, dis,
                                          (unsigned short*)xs_lo,
                                          (unsigned short*)xs_hi,
                                          (unsigned short*)ALw);
    k_gath_lx <<<NN / 8, 256, 0, stream>>>(xs_lo, csr_s, start, cd, dis, ALw, 0);
    k_gath_lx <<<NN / 8, 256, 0, stream>>>(xs_hi, csr_s, start, cd, dis, ALw, 8);
    k_dmm     <<<782, 256, 0, stream>>>((const f16x8*)ALw, (const f16x8*)BzT,
                                        (const f16x8*)BhT, (const f16x8*)WgT,
                                        b_xz, b_hz, b_xh, b_hh, disg,
                                        (unsigned short*)hws_lo,
                                        (unsigned short*)hws_hi);
    k_gath_h  <<<NN / 8, 256, 0, stream>>>(hws_lo, csr_s, start, cd, disg, h2, 0);
    k_gath_h  <<<NN / 8, 256, 0, stream>>>(hws_hi, csr_s, start, cd, disg, h2, 8);
    k_fin     <<<NN / 8, 256, 0, stream>>>(hh, b_gcn, W_lin, b_lin, out);
}

// Round 10
// 176.683 us; speedup vs baseline: 1.5616x; 1.1102x over previous
//
#include <hip/hip_runtime.h>
#include <hip/hip_fp16.h>

#define NN 100000
#define NE 1600000
#define NB 391        // node buckets: node >> 8 (256 nodes/bucket, last=160)
#define NBLK 391      // edge chunks of CHUNK
#define CHUNK 4096

// ---- fp16 helpers ----------------------------------------------------------
__device__ __forceinline__ float h16lo(unsigned u) {
    return __half2float(__ushort_as_half((unsigned short)(u & 0xffffu)));
}
__device__ __forceinline__ float h16hi(unsigned u) {
    return __half2float(__ushort_as_half((unsigned short)(u >> 16)));
}
__device__ __forceinline__ unsigned short h16(float f) {
    return __half_as_ushort(__float2half(f));
}
__device__ __forceinline__ unsigned pack2h(float a, float b) {
    return (unsigned)h16(a) | ((unsigned)h16(b) << 16);
}

using f16x8  = __attribute__((ext_vector_type(8)))  _Float16;
using f32x16 = __attribute__((ext_vector_type(16))) float;

// ---------------------------------------------------------------------------
// B1: per-(chunk,bucket) counts via LDS histograms (no global atomics).
// ---------------------------------------------------------------------------
__global__ __launch_bounds__(256) void k_bcount(const int* __restrict__ src,
                                                const int* __restrict__ dst,
                                                int* __restrict__ counts_d,
                                                int* __restrict__ counts_s) {
    __shared__ int hd[NB], hs[NB];
    int tid = threadIdx.x, blk = blockIdx.x;
    for (int i = tid; i < NB; i += 256) { hd[i] = 0; hs[i] = 0; }
    __syncthreads();
    int e0 = blk * CHUNK, ee = min(e0 + CHUNK, NE);
    for (int e = e0 + tid; e < ee; e += 256) {
        atomicAdd(&hd[dst[e] >> 8], 1);
        atomicAdd(&hs[src[e] >> 8], 1);
    }
    __syncthreads();
    for (int i = tid; i < NB; i += 256) {
        counts_d[blk * NB + i] = hd[i];
        counts_s[blk * NB + i] = hs[i];
    }
}

// ---------------------------------------------------------------------------
// B2: per-bucket exclusive scan over chunks (in place) + bucket totals.
// ---------------------------------------------------------------------------
__global__ __launch_bounds__(256) void k_scan(int* __restrict__ counts_d,
                                              int* __restrict__ counts_s,
                                              int* __restrict__ totd,
                                              int* __restrict__ tots) {
    int b = blockIdx.x;
    int* T; int* tot;
    if (b < NB) { T = counts_d; tot = totd; }
    else        { T = counts_s; tot = tots; b -= NB; }
    __shared__ int sd[256];
    int tid = threadIdx.x;
    int carry = 0;
    for (int base = 0; base < NBLK; base += 256) {
        int idx = base + tid;
        int v = (idx < NBLK) ? T[idx * NB + b] : 0;
        sd[tid] = v;
        __syncthreads();
        for (int off = 1; off < 256; off <<= 1) {
            int t = (tid >= off) ? sd[tid - off] : 0;
            __syncthreads();
            sd[tid] += t;
            __syncthreads();
        }
        if (idx < NBLK) T[idx * NB + b] = carry + sd[tid] - v;
        int bt = sd[255];
        __syncthreads();
        carry += bt;
    }
    if (tid == 0) tot[b] = carry;
}

// ---------------------------------------------------------------------------
// B3: exclusive scan of bucket totals -> bucket base (+ sentinel = NE).
// ---------------------------------------------------------------------------
__global__ __launch_bounds__(256) void k_scan2(const int* __restrict__ totd,
                                               int* __restrict__ based,
                                               const int* __restrict__ tots,
                                               int* __restrict__ bases) {
    const int* T = blockIdx.x ? tots : totd;
    int* B = blockIdx.x ? bases : based;
    __shared__ int sd[256];
    int tid = threadIdx.x;
    int carry = 0;
    for (int base = 0; base < NB; base += 256) {
        int idx = base + tid;
        int v = (idx < NB) ? T[idx] : 0;
        sd[tid] = v;
        __syncthreads();
        for (int off = 1; off < 256; off <<= 1) {
            int t = (tid >= off) ? sd[tid - off] : 0;
            __syncthreads();
            sd[tid] += t;
            __syncthreads();
        }
        if (idx < NB) B[idx] = carry + sd[tid] - v;
        int bt = sd[255];
        __syncthreads();
        carry += bt;
    }
    if (tid == 0) B[NB] = carry;   // == NE
}

// ---------------------------------------------------------------------------
// B4: scatter edges into bucketed lists with LDS cursors (no global atomics).
// ---------------------------------------------------------------------------
__global__ __launch_bounds__(256) void k_bscatter(
        const int* __restrict__ src, const int* __restrict__ dst,
        const int* __restrict__ counts_d, const int* __restrict__ counts_s,
        const int* __restrict__ based, const int* __restrict__ bases,
        unsigned* __restrict__ bkd, unsigned char* __restrict__ bks) {
    __shared__ int cud[NB], cus[NB];
    int tid = threadIdx.x, blk = blockIdx.x;
    for (int i = tid; i < NB; i += 256) {
        cud[i] = based[i] + counts_d[blk * NB + i];
        cus[i] = bases[i] + counts_s[blk * NB + i];
    }
    __syncthreads();
    int e0 = blk * CHUNK, ee = min(e0 + CHUNK, NE);
    for (int e = e0 + tid; e < ee; e += 256) {
        int s = src[e], d = dst[e];
        int p = atomicAdd(&cud[d >> 8], 1);
        bkd[p] = ((unsigned)(d & 255) << 17) | (unsigned)s;
        int q = atomicAdd(&cus[s >> 8], 1);
        bks[q] = (unsigned char)(s & 255);
    }
}

// ---------------------------------------------------------------------------
// B5 (FUSED p2d+p2s+norm): per-bucket in-degree, CSR start/scatter, and
// normalizers.  dis from src-side hist, disg from dst-side hist.
// ---------------------------------------------------------------------------
__global__ __launch_bounds__(256) void k_p2(const unsigned* __restrict__ bkd,
                                            const int* __restrict__ based,
                                            const unsigned char* __restrict__ bks,
                                            const int* __restrict__ bases,
                                            int* __restrict__ cd,
                                            int* __restrict__ start,
                                            int* __restrict__ csr_s,
                                            float* __restrict__ dis,
                                            float* __restrict__ disg) {
    __shared__ int hist[256], scn[256], hs[256];
    int b = blockIdx.x, tid = threadIdx.x;
    hist[tid] = 0; hs[tid] = 0;
    __syncthreads();
    int eb = based[b], ee = based[b + 1];
    for (int e = eb + tid; e < ee; e += 256)
        atomicAdd(&hist[bkd[e] >> 17], 1);
    int sb = bases[b], se = bases[b + 1];
    for (int e = sb + tid; e < se; e += 256)
        atomicAdd(&hs[bks[e]], 1);
    __syncthreads();
    int c = hist[tid];
    scn[tid] = c;
    __syncthreads();
    for (int off = 1; off < 256; off <<= 1) {
        int t = (tid >= off) ? scn[tid - off] : 0;
        __syncthreads();
        scn[tid] += t;
        __syncthreads();
    }
    int excl = scn[tid] - c;
    int node = (b << 8) + tid;
    if (node < NN) {
        cd[node] = c;
        start[node] = eb + excl;
        int oc = hs[tid];
        dis[node]  = oc > 0 ? rsqrtf((float)oc) : 0.0f;
        disg[node] = rsqrtf((float)c + 1.0f);
    }
    __syncthreads();              // all hs reads done
    hs[tid] = eb + excl;          // reuse as cursor
    __syncthreads();
    for (int e = eb + tid; e < ee; e += 256) {
        unsigned pk = bkd[e];
        int p = atomicAdd(&hs[pk >> 17], 1);
        csr_s[p] = (int)(pk & 0x1FFFFu);
    }
}

// ---------------------------------------------------------------------------
// K_cvt (+wcvt folded in block NN*32/256): fp16 tables.
//   xs_lo/xs_hi: SCALED gather tables (dis[s]*x), feature-split 16+16.
//   AL x-half (k=0..31); Lx half written by k_gath_lx.
//   Block 12500: transposed fp16 weight tables BzT/BhT/WgT.
// ---------------------------------------------------------------------------
__global__ __launch_bounds__(256) void k_cvt(const float* __restrict__ x,
                                             const float* __restrict__ dis,
                                             unsigned short* __restrict__ xs_lo,
                                             unsigned short* __restrict__ xs_hi,
                                             unsigned short* __restrict__ ALu,
                                             const float* __restrict__ W_xz,
                                             const float* __restrict__ W_xh,
                                             const float* __restrict__ W_gcn,
                                             unsigned short* __restrict__ BzT,
                                             unsigned short* __restrict__ BhT,
                                             unsigned short* __restrict__ WgT) {
    int tid = threadIdx.x;
    int i = blockIdx.x * 256 + tid;
    if (i < NN * 32) {
        int node = i >> 5, f = i & 31;
        float xv = x[i];
        ALu[node * 64 + f] = h16(xv);
        unsigned short hsv = h16(xv * dis[node]);
        if (f < 16) xs_lo[node * 16 + f] = hsv;
        else        xs_hi[node * 16 + (f - 16)] = hsv;
    } else if (blockIdx.x == (NN * 32) / 256) {
        for (int idx = tid; idx < 2048; idx += 256) {
            int f = idx >> 6, k = idx & 63;
            float vz = (k < 32) ? W_xz[k * 32 + f] : W_xz[1024 + (k - 32) * 32 + f];
            float vh = (k < 32) ? W_xh[k * 32 + f] : W_xh[1024 + (k - 32) * 32 + f];
            BzT[idx] = h16(vz);
            BhT[idx] = h16(vh);
        }
        for (int idx = tid; idx < 1024; idx += 256) {
            int f = idx >> 5, k = idx & 31;
            WgT[idx] = h16(W_gcn[k * 32 + f]);
        }
    }
}

// ---------------------------------------------------------------------------
// K_gath_lx: XCD-split single launch, uint2 (8B) gathers.
//   half = (blk>>2)&1  ->  XCDs 0-3 serve xs_lo, XCDs 4-7 serve xs_hi
//   (blockIdx&7 -> XCD round-robin; mapping change affects speed only).
// 32-lane group per node; 4 lanes/edge (c4 = uint2 col); 16 edges in flight.
// Writes Lx half-row into AL (k=32..63), pre-multiplied by -dis[dst].
// ---------------------------------------------------------------------------
__global__ __launch_bounds__(256) void k_gath_lx(const uint2* __restrict__ xs_lo2,
                                                 const uint2* __restrict__ xs_hi2,
                                                 const int* __restrict__ csr_s,
                                                 const int* __restrict__ start,
                                                 const int* __restrict__ cd,
                                                 const float* __restrict__ dis,
                                                 unsigned* __restrict__ ALw) {
    int tid = threadIdx.x, blk = blockIdx.x;
    int half = (blk >> 2) & 1;
    int oct = (blk >> 3) * 4 + (blk & 3);          // [0, 12500)
    int node = oct * 8 + (tid >> 5);
    int lane = tid & 31, grp = lane >> 2, c4 = lane & 3;
    int st = start[node], cn = cd[node];
    const uint2* tab = half ? xs_hi2 : xs_lo2;

    float a0 = 0.f, a1 = 0.f, a2 = 0.f, a3 = 0.f;
    for (int j = 0; j < cn; j += 16) {
        int e0 = j + grp, e1 = j + 8 + grp;
        int c0 = e0 < cn ? e0 : cn - 1;  float m0 = e0 < cn ? 1.0f : 0.0f;
        int c1 = e1 < cn ? e1 : cn - 1;  float m1 = e1 < cn ? 1.0f : 0.0f;
        int s0 = csr_s[st + c0], s1 = csr_s[st + c1];
        uint2 v0 = tab[s0 * 4 + c4];
        uint2 v1 = tab[s1 * 4 + c4];
        a0 = fmaf(m0, h16lo(v0.x), a0);  a1 = fmaf(m0, h16hi(v0.x), a1);
        a2 = fmaf(m0, h16lo(v0.y), a2);  a3 = fmaf(m0, h16hi(v0.y), a3);
        a0 = fmaf(m1, h16lo(v1.x), a0);  a1 = fmaf(m1, h16hi(v1.x), a1);
        a2 = fmaf(m1, h16lo(v1.y), a2);  a3 = fmaf(m1, h16hi(v1.y), a3);
    }
#pragma unroll
    for (int off = 4; off < 32; off <<= 1) {
        a0 += __shfl_xor(a0, off, 32);
        a1 += __shfl_xor(a1, off, 32);
        a2 += __shfl_xor(a2, off, 32);
        a3 += __shfl_xor(a3, off, 32);
    }
    if (lane < 4) {      // c4 == lane
        float w = -dis[node];
        int base = node * 32 + 16 + half * 8 + 2 * lane;
        ALw[base]     = pack2h(w * a0, w * a1);
        ALw[base + 1] = pack2h(w * a2, w * a3);
    }
}

// ---------------------------------------------------------------------------
// K_dmm: MFMA dense phase (unchanged from R8, passing).  Per wave: 32 nodes.
// ---------------------------------------------------------------------------
__global__ __launch_bounds__(256) void k_dmm(
        const f16x8* __restrict__ AL,
        const f16x8* __restrict__ BzT,
        const f16x8* __restrict__ BhT,
        const f16x8* __restrict__ WgT,
        const float* __restrict__ b_xz, const float* __restrict__ b_hz,
        const float* __restrict__ b_xh, const float* __restrict__ b_hh,
        const float* __restrict__ disg,
        unsigned short* __restrict__ hws_lo,
        unsigned short* __restrict__ hws_hi) {
    __shared__ unsigned short Hl[4 * 1280];   // per-wave 32 x 40 u16 (80B pad)
    int tid = threadIdx.x;
    int wv = blockIdx.x * 4 + (tid >> 6);
    if (wv > 3124) wv = 3124;                 // dup tail wave: same writes, safe
    int l = tid & 63, mrow = l & 31, hi = l >> 5;
    int n0 = wv * 32;
    unsigned short* Hw = Hl + (tid >> 6) * 1280;

    f32x16 accz = {}, acct = {};
    const f16x8* Arow = AL + (n0 + mrow) * 8 + hi;
#pragma unroll
    for (int c = 0; c < 4; ++c) {
        f16x8 a = Arow[c * 2];
        accz = __builtin_amdgcn_mfma_f32_32x32x16_f16(a, BzT[mrow * 8 + c * 2 + hi], accz, 0, 0, 0);
        acct = __builtin_amdgcn_mfma_f32_32x32x16_f16(a, BhT[mrow * 8 + c * 2 + hi], acct, 0, 0, 0);
    }
    float bz = b_xz[mrow] + b_hz[mrow];
    float bh = b_xh[mrow] + b_hh[mrow];
#pragma unroll
    for (int j = 0; j < 16; ++j) {
        float z = accz[j] + bz, t = acct[j] + bh;
        float Z = 1.0f / (1.0f + expf(-z));
        float H = (1.0f - Z) * tanhf(t);
        int r = (j & 3) + 8 * (j >> 2) + 4 * hi;
        Hw[r * 40 + mrow] = h16(H);          // H^T staging (row=node, col=f)
    }
    f32x16 acch = {};
#pragma unroll
    for (int c = 0; c < 2; ++c) {
        f16x8 hfrag = *reinterpret_cast<const f16x8*>(&Hw[mrow * 40 + c * 16 + hi * 8]);
        acch = __builtin_amdgcn_mfma_f32_32x32x16_f16(hfrag, WgT[mrow * 4 + c * 2 + hi], acch, 0, 0, 0);
    }
#pragma unroll
    for (int j = 0; j < 16; ++j) {
        int r = (j & 3) + 8 * (j >> 2) + 4 * hi;
        int node = n0 + r;
        unsigned short hv = h16(disg[node] * acch[j]);
        if (mrow < 16) hws_lo[node * 16 + mrow] = hv;
        else           hws_hi[node * 16 + (mrow - 16)] = hv;
    }
}

// ---------------------------------------------------------------------------
// K_gath_h: XCD-split single launch + FUSED GCN epilogue.
// Per half: acc_f = disg*(sum_e hws[src] + hws[node]);  the relu/W_lin dot
// distributes over feature halves -> per-node partial scalar pf[half][node].
// ---------------------------------------------------------------------------
__global__ __launch_bounds__(256) void k_gath_h(const uint2* __restrict__ hws_lo2,
                                                const uint2* __restrict__ hws_hi2,
                                                const int* __restrict__ csr_s,
                                                const int* __restrict__ start,
                                                const int* __restrict__ cd,
                                                const float* __restrict__ disg,
                                                const float* __restrict__ b_gcn,
                                                const float* __restrict__ W_lin,
                                                float* __restrict__ pf) {
    int tid = threadIdx.x, blk = blockIdx.x;
    int half = (blk >> 2) & 1;
    int oct = (blk >> 3) * 4 + (blk & 3);
    int node = oct * 8 + (tid >> 5);
    int lane = tid & 31, grp = lane >> 2, c4 = lane & 3;
    int st = start[node], cn = cd[node];
    const uint2* tab = half ? hws_hi2 : hws_lo2;

    float a0 = 0.f, a1 = 0.f, a2 = 0.f, a3 = 0.f;
    for (int j = 0; j < cn; j += 16) {
        int e0 = j + grp, e1 = j + 8 + grp;
        int c0 = e0 < cn ? e0 : cn - 1;  float m0 = e0 < cn ? 1.0f : 0.0f;
        int c1 = e1 < cn ? e1 : cn - 1;  float m1 = e1 < cn ? 1.0f : 0.0f;
        int s0 = csr_s[st + c0], s1 = csr_s[st + c1];
        uint2 v0 = tab[s0 * 4 + c4];
        uint2 v1 = tab[s1 * 4 + c4];
        a0 = fmaf(m0, h16lo(v0.x), a0);  a1 = fmaf(m0, h16hi(v0.x), a1);
        a2 = fmaf(m0, h16lo(v0.y), a2);  a3 = fmaf(m0, h16hi(v0.y), a3);
        a0 = fmaf(m1, h16lo(v1.x), a0);  a1 = fmaf(m1, h16hi(v1.x), a1);
        a2 = fmaf(m1, h16lo(v1.y), a2);  a3 = fmaf(m1, h16hi(v1.y), a3);
    }
#pragma unroll
    for (int off = 4; off < 32; off <<= 1) {
        a0 += __shfl_xor(a0, off, 32);
        a1 += __shfl_xor(a1, off, 32);
        a2 += __shfl_xor(a2, off, 32);
        a3 += __shfl_xor(a3, off, 32);
    }
    // self row (pre-scaled by disg[src]=disg[node]) — same cols for all lanes
    uint2 sv = tab[node * 4 + c4];
    float dg = disg[node];
    int f0 = half * 16 + 4 * c4;
    float h0 = dg * (a0 + h16lo(sv.x)) + b_gcn[f0];
    float h1 = dg * (a1 + h16hi(sv.x)) + b_gcn[f0 + 1];
    float h2v = dg * (a2 + h16lo(sv.y)) + b_gcn[f0 + 2];
    float h3 = dg * (a3 + h16hi(sv.y)) + b_gcn[f0 + 3];
    float p = fmaxf(h0, 0.0f) * W_lin[f0]
            + fmaxf(h1, 0.0f) * W_lin[f0 + 1]
            + fmaxf(h2v, 0.0f) * W_lin[f0 + 2]
            + fmaxf(h3, 0.0f) * W_lin[f0 + 3];
    p += __shfl_xor(p, 1, 32);
    p += __shfl_xor(p, 2, 32);
    if (lane == 0) pf[half * NN + node] = p;
}

// ---------------------------------------------------------------------------
// K_fin2: out[node] = pf_lo + pf_hi + b_lin
// ---------------------------------------------------------------------------
__global__ __launch_bounds__(256) void k_fin2(const float* __restrict__ pf,
                                              const float* __restrict__ b_lin,
                                              float* __restrict__ out) {
    int i = blockIdx.x * 256 + threadIdx.x;
    if (i < NN) out[i] = pf[i] + pf[NN + i] + b_lin[0];
}

extern "C" void kernel_launch(void* const* d_in, const int* in_sizes, int n_in,
                              void* d_out, int out_size, void* d_ws, size_t ws_size,
                              hipStream_t stream) {
    const float* x     = (const float*)d_in[0];
    const int*   ei    = (const int*)d_in[1];
    const int*   src   = ei;
    const int*   dst   = ei + NE;
    const float* W_xz  = (const float*)d_in[2];
    const float* b_xz  = (const float*)d_in[3];
    const float* b_hz  = (const float*)d_in[5];
    // W_xr/b_xr/W_hr/b_hr (d_in[6..9]) are dead: R only multiplies H0 == 0.
    const float* W_xh  = (const float*)d_in[10];
    const float* b_xh  = (const float*)d_in[11];
    const float* b_hh  = (const float*)d_in[13];
    const float* W_gcn = (const float*)d_in[14];
    const float* b_gcn = (const float*)d_in[15];
    const float* W_lin = (const float*)d_in[16];
    const float* b_lin = (const float*)d_in[17];
    float* out = (float*)d_out;

    // Workspace (4B words), every array fully written before read (no memsets).
    // Alias: xs_lo/xs_hi overlay bkd (dead after k_p2).
    // NOTE (R9 bug fix): BzT/BhT are 2048 ushorts = 1024 WORDS each, WgT is
    // 1024 ushorts = 512 words.  R9 under-allocated (512/512/256), so BhT's
    // writes clobbered BzT's k>=32 half -> absmax 0.4.
    int* w = (int*)d_ws;
    int* counts_d = w;                    w += 160000;          // NBLK*NB=152881
    int* counts_s = w;                    w += 160000;
    int* totd     = w;                    w += 512;
    int* tots     = w;                    w += 512;
    int* based    = w;                    w += 512;             // NB+1
    int* bases    = w;                    w += 512;
    int* cd       = w;                    w += NN;
    int* start    = w;                    w += NN;
    float* dis    = (float*)w;            w += NN;
    float* disg   = (float*)w;            w += NN;
    float* pf     = (float*)w;            w += 2 * NN;          // partial dots
    unsigned short* hws_lo = (unsigned short*)w;  w += 8 * NN;  // fp16 tables
    unsigned short* hws_hi = (unsigned short*)w;  w += 8 * NN;
    unsigned* ALw  = (unsigned*)w;        w += 32 * NN;         // [x|Lx] fp16 rows
    unsigned* bkd  = (unsigned*)w;        w += NE;              // packed dst list
    unsigned char* bks = (unsigned char*)w; w += NE / 4;        // byte src list
    int* csr_s    = w;                    w += NE;
    unsigned short* BzT = (unsigned short*)w; w += 1024;        // 32f x 64k fp16
    unsigned short* BhT = (unsigned short*)w; w += 1024;
    unsigned short* WgT = (unsigned short*)w; w += 512;         // 32f x 32k fp16
    unsigned short* xs_lo = (unsigned short*)bkd;               // alias, 8N words
    unsigned short* xs_hi = (unsigned short*)(bkd + 8 * NN);    // next 8N words

    k_bcount  <<<NBLK, 256, 0, stream>>>(src, dst, counts_d, counts_s);
    k_scan    <<<2 * NB, 256, 0, stream>>>(counts_d, counts_s, totd, tots);
    k_scan2   <<<2, 256, 0, stream>>>(totd, based, tots, bases);
    k_bscatter<<<NBLK, 256, 0, stream>>>(src, dst, counts_d, counts_s,
                                         based, bases, bkd, bks);
    k_p2      <<<NB, 256, 0, stream>>>(bkd, based, bks, bases,
                                       cd, start, csr_s, dis, disg);
    k_cvt     <<<(NN * 32) / 256 + 1, 256, 0, stream>>>(x, dis, xs_lo, xs_hi,
                                       (unsigned short*)ALw,
                                       W_xz, W_xh, W_gcn, BzT, BhT, WgT);
    k_gath_lx <<<25000, 256, 0, stream>>>((const uint2*)xs_lo, (const uint2*)xs_hi,
                                          csr_s, start, cd, dis, ALw);
    k_dmm     <<<782, 256, 0, stream>>>((const f16x8*)ALw, (const f16x8*)BzT,
                                        (const f16x8*)BhT, (const f16x8*)WgT,
                                        b_xz, b_hz, b_xh, b_hh, disg,
                                        hws_lo, hws_hi);
    k_gath_h  <<<25000, 256, 0, stream>>>((const uint2*)hws_lo, (const uint2*)hws_hi,
                                          csr_s, start, cd, disg,
                                          b_gcn, W_lin, pf);
    k_fin2    <<<(NN + 255) / 256, 256, 0, stream>>>(pf, b_lin, out);
}

// Round 11
// 175.204 us; speedup vs baseline: 1.5748x; 1.0084x over previous
//
#include <hip/hip_runtime.h>
#include <hip/hip_fp16.h>

#define NN 100000
#define NE 1600000
#define NB 391        // node buckets: node >> 8 (256 nodes/bucket, last=160)
#define NBLK 391      // edge chunks of CHUNK
#define CHUNK 4096
#define ASTR 8192     // arena stride/bucket; counts are ~Bin(1.6M,256/1e5):
                      // mean 4096, sd 64 -> 8192 is +64 sd, cannot overflow

// ---- fp16 helpers ----------------------------------------------------------
__device__ __forceinline__ float h16lo(unsigned u) {
    return __half2float(__ushort_as_half((unsigned short)(u & 0xffffu)));
}
__device__ __forceinline__ float h16hi(unsigned u) {
    return __half2float(__ushort_as_half((unsigned short)(u >> 16)));
}
__device__ __forceinline__ unsigned short h16(float f) {
    return __half_as_ushort(__float2half(f));
}
__device__ __forceinline__ unsigned pack2h(float a, float b) {
    return (unsigned)h16(a) | ((unsigned)h16(b) << 16);
}

using f16x8  = __attribute__((ext_vector_type(8)))  _Float16;
using f32x16 = __attribute__((ext_vector_type(16))) float;

// ---------------------------------------------------------------------------
// B1 (FUSED count+scan+scatter): per-chunk LDS histograms; ONE global
// atomicAdd per (block,bucket) claims a contiguous run in the bucket's
// fixed-stride arena; LDS cursors place edges.  No counts tables, no scans.
//   dst arena: packed u32 = (dst&255)<<17 | src   (src < 2^17)
//   src arena: 1 byte = src&255 (downstream needs only per-node counts)
// Final cur_d[b]/cur_s[b] = bucket totals.
// ---------------------------------------------------------------------------
__global__ __launch_bounds__(256) void k_bucket(
        const int* __restrict__ src, const int* __restrict__ dst,
        int* __restrict__ cur_d, int* __restrict__ cur_s,
        unsigned* __restrict__ bkd, unsigned char* __restrict__ bks) {
    __shared__ int hd[NB], hs[NB], bd[NB], bs[NB];
    int tid = threadIdx.x, blk = blockIdx.x;
    for (int i = tid; i < NB; i += 256) { hd[i] = 0; hs[i] = 0; }
    __syncthreads();
    int e0 = blk * CHUNK, ee = min(e0 + CHUNK, NE);
    for (int e = e0 + tid; e < ee; e += 256) {
        atomicAdd(&hd[dst[e] >> 8], 1);
        atomicAdd(&hs[src[e] >> 8], 1);
    }
    __syncthreads();
    for (int i = tid; i < NB; i += 256) {
        int c = hd[i];
        bd[i] = c ? atomicAdd(&cur_d[i], c) : 0;
        hd[i] = 0;
        int c2 = hs[i];
        bs[i] = c2 ? atomicAdd(&cur_s[i], c2) : 0;
        hs[i] = 0;
    }
    __syncthreads();
    for (int e = e0 + tid; e < ee; e += 256) {
        int s = src[e], d = dst[e];
        int bu = d >> 8;
        int p = bd[bu] + atomicAdd(&hd[bu], 1);
        bkd[bu * ASTR + p] = ((unsigned)(d & 255) << 17) | (unsigned)s;
        int bv = s >> 8;
        int q = bs[bv] + atomicAdd(&hs[bv], 1);
        bks[bv * ASTR + q] = (unsigned char)(s & 255);
    }
}

// ---------------------------------------------------------------------------
// B2: 1-block exclusive scan of the 391 dst-bucket totals -> csr_s bases.
// ---------------------------------------------------------------------------
__global__ __launch_bounds__(256) void k_scanb(const int* __restrict__ cur_d,
                                               int* __restrict__ based) {
    __shared__ int sd[256];
    int tid = threadIdx.x;
    int carry = 0;
    for (int base = 0; base < NB; base += 256) {
        int idx = base + tid;
        int v = (idx < NB) ? cur_d[idx] : 0;
        sd[tid] = v;
        __syncthreads();
        for (int off = 1; off < 256; off <<= 1) {
            int t = (tid >= off) ? sd[tid - off] : 0;
            __syncthreads();
            sd[tid] += t;
            __syncthreads();
        }
        if (idx < NB) based[idx] = carry + sd[tid] - v;
        int bt = sd[255];
        __syncthreads();
        carry += bt;
    }
}

// ---------------------------------------------------------------------------
// B3 (FUSED p2d+p2s+norm): per-bucket in-degree, CSR start/scatter (compact),
// and normalizers.  dis from src-side hist, disg from dst-side hist.
// ---------------------------------------------------------------------------
__global__ __launch_bounds__(256) void k_p2(const unsigned* __restrict__ bkd,
                                            const unsigned char* __restrict__ bks,
                                            const int* __restrict__ cur_d,
                                            const int* __restrict__ cur_s,
                                            const int* __restrict__ based,
                                            int* __restrict__ cd,
                                            int* __restrict__ start,
                                            int* __restrict__ csr_s,
                                            float* __restrict__ dis,
                                            float* __restrict__ disg) {
    __shared__ int hist[256], scn[256], hs[256];
    int b = blockIdx.x, tid = threadIdx.x;
    hist[tid] = 0; hs[tid] = 0;
    __syncthreads();
    int eb = b * ASTR, ee = eb + cur_d[b];
    for (int e = eb + tid; e < ee; e += 256)
        atomicAdd(&hist[bkd[e] >> 17], 1);
    int sb = b * ASTR, se = sb + cur_s[b];
    for (int e = sb + tid; e < se; e += 256)
        atomicAdd(&hs[bks[e]], 1);
    __syncthreads();
    int c = hist[tid];
    scn[tid] = c;
    __syncthreads();
    for (int off = 1; off < 256; off <<= 1) {
        int t = (tid >= off) ? scn[tid - off] : 0;
        __syncthreads();
        scn[tid] += t;
        __syncthreads();
    }
    int excl = scn[tid] - c;
    int cb = based[b];
    int node = (b << 8) + tid;
    if (node < NN) {
        cd[node] = c;
        start[node] = cb + excl;
        int oc = hs[tid];
        dis[node]  = oc > 0 ? rsqrtf((float)oc) : 0.0f;
        disg[node] = rsqrtf((float)c + 1.0f);
    }
    __syncthreads();              // all hs reads done
    hs[tid] = cb + excl;          // reuse as csr cursor
    __syncthreads();
    for (int e = eb + tid; e < ee; e += 256) {
        unsigned pk = bkd[e];
        int p = atomicAdd(&hs[pk >> 17], 1);
        csr_s[p] = (int)(pk & 0x1FFFFu);
    }
}

// ---------------------------------------------------------------------------
// K_cvt (+wcvt folded in the extra block): fp16 gather tables only.
//   xs_lo/xs_hi: SCALED tables (dis[s]*x), feature-split 16+16 (3.2MB each).
//   Extra block: transposed fp16 weight tables BzT/BhT/WgT.
// (x-half of the old AL table is gone: k_dmm reads x f32 directly.)
// ---------------------------------------------------------------------------
__global__ __launch_bounds__(256) void k_cvt(const float* __restrict__ x,
                                             const float* __restrict__ dis,
                                             unsigned short* __restrict__ xs_lo,
                                             unsigned short* __restrict__ xs_hi,
                                             const float* __restrict__ W_xz,
                                             const float* __restrict__ W_xh,
                                             const float* __restrict__ W_gcn,
                                             unsigned short* __restrict__ BzT,
                                             unsigned short* __restrict__ BhT,
                                             unsigned short* __restrict__ WgT) {
    int tid = threadIdx.x;
    int i = blockIdx.x * 256 + tid;
    if (i < NN * 32) {
        int node = i >> 5, f = i & 31;
        unsigned short hsv = h16(x[i] * dis[node]);
        if (f < 16) xs_lo[node * 16 + f] = hsv;
        else        xs_hi[node * 16 + (f - 16)] = hsv;
    } else if (blockIdx.x == (NN * 32) / 256) {
        for (int idx = tid; idx < 2048; idx += 256) {
            int f = idx >> 6, k = idx & 63;
            float vz = (k < 32) ? W_xz[k * 32 + f] : W_xz[1024 + (k - 32) * 32 + f];
            float vh = (k < 32) ? W_xh[k * 32 + f] : W_xh[1024 + (k - 32) * 32 + f];
            BzT[idx] = h16(vz);
            BhT[idx] = h16(vh);
        }
        for (int idx = tid; idx < 1024; idx += 256) {
            int f = idx >> 5, k = idx & 31;
            WgT[idx] = h16(W_gcn[k * 32 + f]);
        }
    }
}

// ---------------------------------------------------------------------------
// K_gath_lx: XCD-split single launch, uint2 (8B) gathers.
//   half = (blk>>2)&1 -> XCDs 0-3 serve xs_lo, XCDs 4-7 serve xs_hi.
// Writes the Lx half-row into compact Lxh table (fp16, 32/node), pre-
// multiplied by -dis[dst].
// ---------------------------------------------------------------------------
__global__ __launch_bounds__(256) void k_gath_lx(const uint2* __restrict__ xs_lo2,
                                                 const uint2* __restrict__ xs_hi2,
                                                 const int* __restrict__ csr_s,
                                                 const int* __restrict__ start,
                                                 const int* __restrict__ cd,
                                                 const float* __restrict__ dis,
                                                 unsigned* __restrict__ Lxh) {
    int tid = threadIdx.x, blk = blockIdx.x;
    int half = (blk >> 2) & 1;
    int oct = (blk >> 3) * 4 + (blk & 3);          // [0, 12500)
    int node = oct * 8 + (tid >> 5);
    int lane = tid & 31, grp = lane >> 2, c4 = lane & 3;
    int st = start[node], cn = cd[node];
    const uint2* tab = half ? xs_hi2 : xs_lo2;

    float a0 = 0.f, a1 = 0.f, a2 = 0.f, a3 = 0.f;
    for (int j = 0; j < cn; j += 16) {
        int e0 = j + grp, e1 = j + 8 + grp;
        int c0 = e0 < cn ? e0 : cn - 1;  float m0 = e0 < cn ? 1.0f : 0.0f;
        int c1 = e1 < cn ? e1 : cn - 1;  float m1 = e1 < cn ? 1.0f : 0.0f;
        int s0 = csr_s[st + c0], s1 = csr_s[st + c1];
        uint2 v0 = tab[s0 * 4 + c4];
        uint2 v1 = tab[s1 * 4 + c4];
        a0 = fmaf(m0, h16lo(v0.x), a0);  a1 = fmaf(m0, h16hi(v0.x), a1);
        a2 = fmaf(m0, h16lo(v0.y), a2);  a3 = fmaf(m0, h16hi(v0.y), a3);
        a0 = fmaf(m1, h16lo(v1.x), a0);  a1 = fmaf(m1, h16hi(v1.x), a1);
        a2 = fmaf(m1, h16lo(v1.y), a2);  a3 = fmaf(m1, h16hi(v1.y), a3);
    }
#pragma unroll
    for (int off = 4; off < 32; off <<= 1) {
        a0 += __shfl_xor(a0, off, 32);
        a1 += __shfl_xor(a1, off, 32);
        a2 += __shfl_xor(a2, off, 32);
        a3 += __shfl_xor(a3, off, 32);
    }
    if (lane < 4) {      // c4 == lane; feature f0 = half*16 + 4*lane
        float w = -dis[node];
        int base = node * 16 + half * 8 + 2 * lane;   // uint units
        Lxh[base]     = pack2h(w * a0, w * a1);
        Lxh[base + 1] = pack2h(w * a2, w * a3);
    }
}

// ---------------------------------------------------------------------------
// K_dmm: MFMA dense phase.  Per wave: 32 nodes.
//   A operand: k=0..31 from x (f32, converted in-register);
//              k=32..63 from Lxh (fp16 fragments, 16B loads).
//   [z|t] = A @ [BzT|BhT]; H = (1-sigmoid)*tanh; hw = H @ Wg (LDS transpose);
//   hws tables = fp16(disg*hw).
// C/D layout: col=lane&31, row=(reg&3)+8*(reg>>2)+4*(lane>>5)  [m74/m101].
// ---------------------------------------------------------------------------
__global__ __launch_bounds__(256) void k_dmm(
        const float* __restrict__ x,
        const f16x8* __restrict__ Lxh,    // [node*4 + (c-2)*2 + hi]
        const f16x8* __restrict__ BzT,
        const f16x8* __restrict__ BhT,
        const f16x8* __restrict__ WgT,
        const float* __restrict__ b_xz, const float* __restrict__ b_hz,
        const float* __restrict__ b_xh, const float* __restrict__ b_hh,
        const float* __restrict__ disg,
        unsigned short* __restrict__ hws_lo,
        unsigned short* __restrict__ hws_hi) {
    __shared__ unsigned short Hl[4 * 1280];   // per-wave 32 x 40 u16 (80B pad)
    int tid = threadIdx.x;
    int wv = blockIdx.x * 4 + (tid >> 6);
    if (wv > 3124) wv = 3124;                 // dup tail wave: same writes, safe
    int l = tid & 63, mrow = l & 31, hi = l >> 5;
    int n0 = wv * 32;
    unsigned short* Hw = Hl + (tid >> 6) * 1280;

    f32x16 accz = {}, acct = {};
    const float* xrow = x + (size_t)(n0 + mrow) * 32;
#pragma unroll
    for (int c = 0; c < 2; ++c) {
        f16x8 a;
        const float* p = xrow + c * 16 + hi * 8;
#pragma unroll
        for (int e = 0; e < 8; ++e) a[e] = (_Float16)p[e];
        accz = __builtin_amdgcn_mfma_f32_32x32x16_f16(a, BzT[mrow * 8 + c * 2 + hi], accz, 0, 0, 0);
        acct = __builtin_amdgcn_mfma_f32_32x32x16_f16(a, BhT[mrow * 8 + c * 2 + hi], acct, 0, 0, 0);
    }
    const f16x8* Lrow = Lxh + (size_t)(n0 + mrow) * 4;
#pragma unroll
    for (int c = 2; c < 4; ++c) {
        f16x8 a = Lrow[(c - 2) * 2 + hi];
        accz = __builtin_amdgcn_mfma_f32_32x32x16_f16(a, BzT[mrow * 8 + c * 2 + hi], accz, 0, 0, 0);
        acct = __builtin_amdgcn_mfma_f32_32x32x16_f16(a, BhT[mrow * 8 + c * 2 + hi], acct, 0, 0, 0);
    }
    float bz = b_xz[mrow] + b_hz[mrow];
    float bh = b_xh[mrow] + b_hh[mrow];
#pragma unroll
    for (int j = 0; j < 16; ++j) {
        float z = accz[j] + bz, t = acct[j] + bh;
        float Z = 1.0f / (1.0f + expf(-z));
        float H = (1.0f - Z) * tanhf(t);
        int r = (j & 3) + 8 * (j >> 2) + 4 * hi;
        Hw[r * 40 + mrow] = h16(H);          // H^T staging (row=node, col=f)
    }
    f32x16 acch = {};
#pragma unroll
    for (int c = 0; c < 2; ++c) {
        f16x8 hfrag = *reinterpret_cast<const f16x8*>(&Hw[mrow * 40 + c * 16 + hi * 8]);
        acch = __builtin_amdgcn_mfma_f32_32x32x16_f16(hfrag, WgT[mrow * 4 + c * 2 + hi], acch, 0, 0, 0);
    }
#pragma unroll
    for (int j = 0; j < 16; ++j) {
        int r = (j & 3) + 8 * (j >> 2) + 4 * hi;
        int node = n0 + r;
        unsigned short hv = h16(disg[node] * acch[j]);
        if (mrow < 16) hws_lo[node * 16 + mrow] = hv;
        else           hws_hi[node * 16 + (mrow - 16)] = hv;
    }
}

// ---------------------------------------------------------------------------
// K_gath_h: XCD-split single launch + FUSED GCN epilogue.
// acc_f = disg*(sum_e hws[src] + hws[node]); relu/W_lin dot distributes over
// feature halves -> per-node partial scalar pf[half][node].
// ---------------------------------------------------------------------------
__global__ __launch_bounds__(256) void k_gath_h(const uint2* __restrict__ hws_lo2,
                                                const uint2* __restrict__ hws_hi2,
                                                const int* __restrict__ csr_s,
                                                const int* __restrict__ start,
                                                const int* __restrict__ cd,
                                                const float* __restrict__ disg,
                                                const float* __restrict__ b_gcn,
                                                const float* __restrict__ W_lin,
                                                float* __restrict__ pf) {
    int tid = threadIdx.x, blk = blockIdx.x;
    int half = (blk >> 2) & 1;
    int oct = (blk >> 3) * 4 + (blk & 3);
    int node = oct * 8 + (tid >> 5);
    int lane = tid & 31, grp = lane >> 2, c4 = lane & 3;
    int st = start[node], cn = cd[node];
    const uint2* tab = half ? hws_hi2 : hws_lo2;

    float a0 = 0.f, a1 = 0.f, a2 = 0.f, a3 = 0.f;
    for (int j = 0; j < cn; j += 16) {
        int e0 = j + grp, e1 = j + 8 + grp;
        int c0 = e0 < cn ? e0 : cn - 1;  float m0 = e0 < cn ? 1.0f : 0.0f;
        int c1 = e1 < cn ? e1 : cn - 1;  float m1 = e1 < cn ? 1.0f : 0.0f;
        int s0 = csr_s[st + c0], s1 = csr_s[st + c1];
        uint2 v0 = tab[s0 * 4 + c4];
        uint2 v1 = tab[s1 * 4 + c4];
        a0 = fmaf(m0, h16lo(v0.x), a0);  a1 = fmaf(m0, h16hi(v0.x), a1);
        a2 = fmaf(m0, h16lo(v0.y), a2);  a3 = fmaf(m0, h16hi(v0.y), a3);
        a0 = fmaf(m1, h16lo(v1.x), a0);  a1 = fmaf(m1, h16hi(v1.x), a1);
        a2 = fmaf(m1, h16lo(v1.y), a2);  a3 = fmaf(m1, h16hi(v1.y), a3);
    }
#pragma unroll
    for (int off = 4; off < 32; off <<= 1) {
        a0 += __shfl_xor(a0, off, 32);
        a1 += __shfl_xor(a1, off, 32);
        a2 += __shfl_xor(a2, off, 32);
        a3 += __shfl_xor(a3, off, 32);
    }
    // self row (pre-scaled by disg[src]=disg[node]) — same cols for all lanes
    uint2 sv = tab[node * 4 + c4];
    float dg = disg[node];
    int f0 = half * 16 + 4 * c4;
    float h0 = dg * (a0 + h16lo(sv.x)) + b_gcn[f0];
    float h1 = dg * (a1 + h16hi(sv.x)) + b_gcn[f0 + 1];
    float h2v = dg * (a2 + h16lo(sv.y)) + b_gcn[f0 + 2];
    float h3 = dg * (a3 + h16hi(sv.y)) + b_gcn[f0 + 3];
    float p = fmaxf(h0, 0.0f) * W_lin[f0]
            + fmaxf(h1, 0.0f) * W_lin[f0 + 1]
            + fmaxf(h2v, 0.0f) * W_lin[f0 + 2]
            + fmaxf(h3, 0.0f) * W_lin[f0 + 3];
    p += __shfl_xor(p, 1, 32);
    p += __shfl_xor(p, 2, 32);
    if (lane == 0) pf[half * NN + node] = p;
}

// ---------------------------------------------------------------------------
// K_fin2: out[node] = pf_lo + pf_hi + b_lin
// ---------------------------------------------------------------------------
__global__ __launch_bounds__(256) void k_fin2(const float* __restrict__ pf,
                                              const float* __restrict__ b_lin,
                                              float* __restrict__ out) {
    int i = blockIdx.x * 256 + threadIdx.x;
    if (i < NN) out[i] = pf[i] + pf[NN + i] + b_lin[0];
}

extern "C" void kernel_launch(void* const* d_in, const int* in_sizes, int n_in,
                              void* d_out, int out_size, void* d_ws, size_t ws_size,
                              hipStream_t stream) {
    const float* x     = (const float*)d_in[0];
    const int*   ei    = (const int*)d_in[1];
    const int*   src   = ei;
    const int*   dst   = ei + NE;
    const float* W_xz  = (const float*)d_in[2];
    const float* b_xz  = (const float*)d_in[3];
    const float* b_hz  = (const float*)d_in[5];
    // W_xr/b_xr/W_hr/b_hr (d_in[6..9]) are dead: R only multiplies H0 == 0.
    const float* W_xh  = (const float*)d_in[10];
    const float* b_xh  = (const float*)d_in[11];
    const float* b_hh  = (const float*)d_in[13];
    const float* W_gcn = (const float*)d_in[14];
    const float* b_gcn = (const float*)d_in[15];
    const float* W_lin = (const float*)d_in[16];
    const float* b_lin = (const float*)d_in[17];
    float* out = (float*)d_out;

    // Workspace (4B words), ~37.6 MB.  Only cur_d/cur_s need zeroing (3.1KB).
    // Aliases: xs_lo/xs_hi overlay bkd arena (dead after k_p2); 16N <= NB*ASTR.
    // Sizes audited (R9 lesson): BzT/BhT = 2048 ushorts = 1024 words each,
    // WgT = 1024 ushorts = 512 words.
    int* w = (int*)d_ws;
    int* cur_d = w;                       w += 392;
    int* cur_s = w;                       w += 392;
    int* based = w;                       w += 392;
    int* cd    = w;                       w += NN;
    int* start = w;                       w += NN;
    float* dis  = (float*)w;              w += NN;
    float* disg = (float*)w;              w += NN;
    float* pf   = (float*)w;              w += 2 * NN;
    unsigned short* hws_lo = (unsigned short*)w;  w += 8 * NN;   // 16 fp16/node
    unsigned short* hws_hi = (unsigned short*)w;  w += 8 * NN;
    unsigned* Lxh = (unsigned*)w;         w += 16 * NN;          // 32 fp16/node
    unsigned* bkd = (unsigned*)w;         w += NB * ASTR;        // 3,203,072
    unsigned char* bks = (unsigned char*)w; w += (NB * ASTR) / 4;
    int* csr_s = w;                       w += NE;
    unsigned short* BzT = (unsigned short*)w; w += 1024;         // 32f x 64k
    unsigned short* BhT = (unsigned short*)w; w += 1024;
    unsigned short* WgT = (unsigned short*)w; w += 512;          // 32f x 32k
    unsigned short* xs_lo = (unsigned short*)bkd;                // alias
    unsigned short* xs_hi = (unsigned short*)(bkd + 8 * NN);

    hipMemsetAsync(cur_d, 0, 784 * sizeof(int), stream);

    k_bucket <<<NBLK, 256, 0, stream>>>(src, dst, cur_d, cur_s, bkd, bks);
    k_scanb  <<<1, 256, 0, stream>>>(cur_d, based);
    k_p2     <<<NB, 256, 0, stream>>>(bkd, bks, cur_d, cur_s, based,
                                      cd, start, csr_s, dis, disg);
    k_cvt    <<<(NN * 32) / 256 + 1, 256, 0, stream>>>(x, dis, xs_lo, xs_hi,
                                      W_xz, W_xh, W_gcn, BzT, BhT, WgT);
    k_gath_lx<<<25000, 256, 0, stream>>>((const uint2*)xs_lo, (const uint2*)xs_hi,
                                         csr_s, start, cd, dis, Lxh);
    k_dmm    <<<782, 256, 0, stream>>>(x, (const f16x8*)Lxh, (const f16x8*)BzT,
                                       (const f16x8*)BhT, (const f16x8*)WgT,
                                       b_xz, b_hz, b_xh, b_hh, disg,
                                       hws_lo, hws_hi);
    k_gath_h <<<25000, 256, 0, stream>>>((const uint2*)hws_lo, (const uint2*)hws_hi,
                                         csr_s, start, cd, disg,
                                         b_gcn, W_lin, pf);
    k_fin2   <<<(NN + 255) / 256, 256, 0, stream>>>(pf, b_lin, out);
}

// Round 12
// 152.229 us; speedup vs baseline: 1.8125x; 1.1509x over previous
//
#include <hip/hip_runtime.h>
#include <hip/hip_fp16.h>

#define NN 100000
#define NE 1600000
#define NB 391        // node buckets: node >> 8 (256 nodes/bucket, last=160)
#define NBLK 391      // edge chunks of CHUNK
#define CHUNK 4096
#define BT 1024       // k_bucket block size
#define ASTR 8192     // arena stride/bucket; counts are ~Bin(1.6M,256/1e5):
                      // mean 4096, sd 64 -> 8192 is +64 sd, cannot overflow

// ---- fp16 helpers ----------------------------------------------------------
__device__ __forceinline__ float h16lo(unsigned u) {
    return __half2float(__ushort_as_half((unsigned short)(u & 0xffffu)));
}
__device__ __forceinline__ float h16hi(unsigned u) {
    return __half2float(__ushort_as_half((unsigned short)(u >> 16)));
}
__device__ __forceinline__ unsigned short h16(float f) {
    return __half_as_ushort(__float2half(f));
}
__device__ __forceinline__ unsigned pack2h(float a, float b) {
    return (unsigned)h16(a) | ((unsigned)h16(b) << 16);
}

using f16x8  = __attribute__((ext_vector_type(8)))  _Float16;
using f32x16 = __attribute__((ext_vector_type(16))) float;

// ---------------------------------------------------------------------------
// B1: fused count + LDS counting-sort + coalesced arena write.
// Per chunk: LDS histograms (dst/src buckets) -> LDS exclusive scan ->
// one global atomicAdd per (block,bucket) claims a contiguous arena run ->
// LDS placement (sorted by bucket) -> write-out with consecutive addresses
// within runs (wave-coalesced; each arena line has ~1 writer block).
//   dst arena: packed u32 = (dst&255)<<17 | src   (src < 2^17)
//   src arena: 1 byte = src&255
// Final cur_d[b]/cur_s[b] = bucket totals.
// ---------------------------------------------------------------------------
__global__ __launch_bounds__(BT) void k_bucket(
        const int* __restrict__ src, const int* __restrict__ dst,
        int* __restrict__ cur_d, int* __restrict__ cur_s,
        unsigned* __restrict__ bkd, unsigned char* __restrict__ bks) {
    __shared__ int hd[NB], hs[NB];            // hist, then LDS cursors
    __shared__ int bd[NB], bs[NB];            // claimed global bases
    __shared__ int od[NB], os[NB];            // local exclusive offsets
    __shared__ int t0[512], t1[512];          // scan temps
    __shared__ unsigned       sortd[CHUNK];   // dst-sorted packed entries
    __shared__ unsigned short sbkt [CHUNK];   // bucket id per entry (dst)
    __shared__ unsigned char  sorts[CHUNK];   // src-sorted bytes
    __shared__ unsigned short sbkts[CHUNK];   // bucket id per entry (src)

    int tid = threadIdx.x, blk = blockIdx.x;
    if (tid < NB) { hd[tid] = 0; hs[tid] = 0; }
    __syncthreads();

    int e0 = blk * CHUNK, ee = min(e0 + CHUNK, NE);
    int sv[4], dv[4]; bool va[4];
#pragma unroll
    for (int u = 0; u < 4; ++u) {
        int e = e0 + u * BT + tid;
        va[u] = e < ee;
        if (va[u]) {
            sv[u] = src[e]; dv[u] = dst[e];
            atomicAdd(&hd[dv[u] >> 8], 1);
            atomicAdd(&hs[sv[u] >> 8], 1);
        }
    }
    __syncthreads();

    // exclusive scan of both histograms (Hillis-Steele over padded 512)
    if (tid < 512) {
        t0[tid] = tid < NB ? hd[tid] : 0;
        t1[tid] = tid < NB ? hs[tid] : 0;
    }
    __syncthreads();
    for (int off = 1; off < 512; off <<= 1) {
        int a = 0, b = 0;
        if (tid < 512 && tid >= off) { a = t0[tid - off]; b = t1[tid - off]; }
        __syncthreads();
        if (tid < 512) { t0[tid] += a; t1[tid] += b; }
        __syncthreads();
    }
    if (tid < NB) {
        int c = hd[tid], c2 = hs[tid];
        od[tid] = t0[tid] - c;
        os[tid] = t1[tid] - c2;
        bd[tid] = c  ? atomicAdd(&cur_d[tid], c)  : 0;
        bs[tid] = c2 ? atomicAdd(&cur_s[tid], c2) : 0;
        hd[tid] = od[tid];            // reuse as LDS cursors
        hs[tid] = os[tid];
    }
    __syncthreads();

    // LDS placement (sorted by bucket)
#pragma unroll
    for (int u = 0; u < 4; ++u) if (va[u]) {
        int bu = dv[u] >> 8;
        int p = atomicAdd(&hd[bu], 1);
        sortd[p] = ((unsigned)(dv[u] & 255) << 17) | (unsigned)sv[u];
        sbkt[p]  = (unsigned short)bu;
        int bv = sv[u] >> 8;
        int q = atomicAdd(&hs[bv], 1);
        sorts[q] = (unsigned char)(sv[u] & 255);
        sbkts[q] = (unsigned short)bv;
    }
    __syncthreads();

    // coalesced write-out
    int n = ee - e0;
    for (int i = tid; i < n; i += BT) {
        int b1 = sbkt[i];
        bkd[b1 * ASTR + bd[b1] + (i - od[b1])] = sortd[i];
        int b2 = sbkts[i];
        bks[b2 * ASTR + bs[b2] + (i - os[b2])] = sorts[i];
    }
}

// ---------------------------------------------------------------------------
// B2 (FUSED scanb+p2d+p2s+norm): per-bucket csr base (on-the-fly prefix sum
// of cur_d), in-degree counts, CSR start/scatter (compact), normalizers.
// ---------------------------------------------------------------------------
__global__ __launch_bounds__(256) void k_p2(const unsigned* __restrict__ bkd,
                                            const unsigned char* __restrict__ bks,
                                            const int* __restrict__ cur_d,
                                            const int* __restrict__ cur_s,
                                            int* __restrict__ cd,
                                            int* __restrict__ start,
                                            int* __restrict__ csr_s,
                                            float* __restrict__ dis,
                                            float* __restrict__ disg) {
    __shared__ int hist[256], scn[256], hs[256];
    int b = blockIdx.x, tid = threadIdx.x;
    hist[tid] = 0; hs[tid] = 0;
    // csr base for this bucket = sum_{i<b} cur_d[i]
    int acc = 0;
    for (int i = tid; i < b; i += 256) acc += cur_d[i];
    scn[tid] = acc;
    __syncthreads();
    for (int off = 128; off > 0; off >>= 1) {
        if (tid < off) scn[tid] += scn[tid + off];
        __syncthreads();
    }
    int cb = scn[0];
    __syncthreads();

    int eb = b * ASTR, ee = eb + cur_d[b];
    for (int e = eb + tid; e < ee; e += 256)
        atomicAdd(&hist[bkd[e] >> 17], 1);
    int sb = b * ASTR, se = sb + cur_s[b];
    for (int e = sb + tid; e < se; e += 256)
        atomicAdd(&hs[bks[e]], 1);
    __syncthreads();
    int c = hist[tid];
    scn[tid] = c;
    __syncthreads();
    for (int off = 1; off < 256; off <<= 1) {
        int t = (tid >= off) ? scn[tid - off] : 0;
        __syncthreads();
        scn[tid] += t;
        __syncthreads();
    }
    int excl = scn[tid] - c;
    int node = (b << 8) + tid;
    if (node < NN) {
        cd[node] = c;
        start[node] = cb + excl;
        int oc = hs[tid];
        dis[node]  = oc > 0 ? rsqrtf((float)oc) : 0.0f;
        disg[node] = rsqrtf((float)c + 1.0f);
    }
    __syncthreads();              // all hs reads done
    hs[tid] = cb + excl;          // reuse as csr cursor
    __syncthreads();
    for (int e = eb + tid; e < ee; e += 256) {
        unsigned pk = bkd[e];
        int p = atomicAdd(&hs[pk >> 17], 1);
        csr_s[p] = (int)(pk & 0x1FFFFu);
    }
}

// ---------------------------------------------------------------------------
// K_cvt (+wcvt folded in the extra block): fp16 gather tables.
//   xs_lo/xs_hi: SCALED tables (dis[s]*x), feature-split 16+16 (3.2MB each).
//   Extra block: transposed fp16 weight tables BzT/BhT/WgT.
// ---------------------------------------------------------------------------
__global__ __launch_bounds__(256) void k_cvt(const float* __restrict__ x,
                                             const float* __restrict__ dis,
                                             unsigned short* __restrict__ xs_lo,
                                             unsigned short* __restrict__ xs_hi,
                                             const float* __restrict__ W_xz,
                                             const float* __restrict__ W_xh,
                                             const float* __restrict__ W_gcn,
                                             unsigned short* __restrict__ BzT,
                                             unsigned short* __restrict__ BhT,
                                             unsigned short* __restrict__ WgT) {
    int tid = threadIdx.x;
    int i = blockIdx.x * 256 + tid;
    if (i < NN * 32) {
        int node = i >> 5, f = i & 31;
        unsigned short hsv = h16(x[i] * dis[node]);
        if (f < 16) xs_lo[node * 16 + f] = hsv;
        else        xs_hi[node * 16 + (f - 16)] = hsv;
    } else if (blockIdx.x == (NN * 32) / 256) {
        for (int idx = tid; idx < 2048; idx += 256) {
            int f = idx >> 6, k = idx & 63;
            float vz = (k < 32) ? W_xz[k * 32 + f] : W_xz[1024 + (k - 32) * 32 + f];
            float vh = (k < 32) ? W_xh[k * 32 + f] : W_xh[1024 + (k - 32) * 32 + f];
            BzT[idx] = h16(vz);
            BhT[idx] = h16(vh);
        }
        for (int idx = tid; idx < 1024; idx += 256) {
            int f = idx >> 5, k = idx & 31;
            WgT[idx] = h16(W_gcn[k * 32 + f]);
        }
    }
}

// ---------------------------------------------------------------------------
// K_gath_lx: XCD-split single launch, uint2 (8B) gathers.
// Writes the Lx half-row into compact Lxh table (fp16, 32/node), pre-
// multiplied by -dis[dst].
// ---------------------------------------------------------------------------
__global__ __launch_bounds__(256) void k_gath_lx(const uint2* __restrict__ xs_lo2,
                                                 const uint2* __restrict__ xs_hi2,
                                                 const int* __restrict__ csr_s,
                                                 const int* __restrict__ start,
                                                 const int* __restrict__ cd,
                                                 const float* __restrict__ dis,
                                                 unsigned* __restrict__ Lxh) {
    int tid = threadIdx.x, blk = blockIdx.x;
    int half = (blk >> 2) & 1;
    int oct = (blk >> 3) * 4 + (blk & 3);          // [0, 12500)
    int node = oct * 8 + (tid >> 5);
    int lane = tid & 31, grp = lane >> 2, c4 = lane & 3;
    int st = start[node], cn = cd[node];
    const uint2* tab = half ? xs_hi2 : xs_lo2;

    float a0 = 0.f, a1 = 0.f, a2 = 0.f, a3 = 0.f;
    for (int j = 0; j < cn; j += 16) {
        int e0 = j + grp, e1 = j + 8 + grp;
        int c0 = e0 < cn ? e0 : cn - 1;  float m0 = e0 < cn ? 1.0f : 0.0f;
        int c1 = e1 < cn ? e1 : cn - 1;  float m1 = e1 < cn ? 1.0f : 0.0f;
        int s0 = csr_s[st + c0], s1 = csr_s[st + c1];
        uint2 v0 = tab[s0 * 4 + c4];
        uint2 v1 = tab[s1 * 4 + c4];
        a0 = fmaf(m0, h16lo(v0.x), a0);  a1 = fmaf(m0, h16hi(v0.x), a1);
        a2 = fmaf(m0, h16lo(v0.y), a2);  a3 = fmaf(m0, h16hi(v0.y), a3);
        a0 = fmaf(m1, h16lo(v1.x), a0);  a1 = fmaf(m1, h16hi(v1.x), a1);
        a2 = fmaf(m1, h16lo(v1.y), a2);  a3 = fmaf(m1, h16hi(v1.y), a3);
    }
#pragma unroll
    for (int off = 4; off < 32; off <<= 1) {
        a0 += __shfl_xor(a0, off, 32);
        a1 += __shfl_xor(a1, off, 32);
        a2 += __shfl_xor(a2, off, 32);
        a3 += __shfl_xor(a3, off, 32);
    }
    if (lane < 4) {      // c4 == lane; feature f0 = half*16 + 4*lane
        float w = -dis[node];
        int base = node * 16 + half * 8 + 2 * lane;   // uint units
        Lxh[base]     = pack2h(w * a0, w * a1);
        Lxh[base + 1] = pack2h(w * a2, w * a3);
    }
}

// ---------------------------------------------------------------------------
// K_dmm: MFMA dense phase.  Per wave: 32 nodes.
//   A operand: k=0..31 from x (f32, converted in-register);
//              k=32..63 from Lxh (fp16 fragments, 16B loads).
//   [z|t] = A @ [BzT|BhT]; H = (1-sigmoid)*tanh; hw = H @ Wg (LDS transpose);
//   hws tables = fp16(disg*hw).
// C/D layout: col=lane&31, row=(reg&3)+8*(reg>>2)+4*(lane>>5)  [m74/m101].
// ---------------------------------------------------------------------------
__global__ __launch_bounds__(256) void k_dmm(
        const float* __restrict__ x,
        const f16x8* __restrict__ Lxh,    // [node*4 + (c-2)*2 + hi]
        const f16x8* __restrict__ BzT,
        const f16x8* __restrict__ BhT,
        const f16x8* __restrict__ WgT,
        const float* __restrict__ b_xz, const float* __restrict__ b_hz,
        const float* __restrict__ b_xh, const float* __restrict__ b_hh,
        const float* __restrict__ disg,
        unsigned short* __restrict__ hws_lo,
        unsigned short* __restrict__ hws_hi) {
    __shared__ unsigned short Hl[4 * 1280];   // per-wave 32 x 40 u16 (80B pad)
    int tid = threadIdx.x;
    int wv = blockIdx.x * 4 + (tid >> 6);
    if (wv > 3124) wv = 3124;                 // dup tail wave: same writes, safe
    int l = tid & 63, mrow = l & 31, hi = l >> 5;
    int n0 = wv * 32;
    unsigned short* Hw = Hl + (tid >> 6) * 1280;

    f32x16 accz = {}, acct = {};
    const float* xrow = x + (size_t)(n0 + mrow) * 32;
#pragma unroll
    for (int c = 0; c < 2; ++c) {
        f16x8 a;
        const float* p = xrow + c * 16 + hi * 8;
#pragma unroll
        for (int e = 0; e < 8; ++e) a[e] = (_Float16)p[e];
        accz = __builtin_amdgcn_mfma_f32_32x32x16_f16(a, BzT[mrow * 8 + c * 2 + hi], accz, 0, 0, 0);
        acct = __builtin_amdgcn_mfma_f32_32x32x16_f16(a, BhT[mrow * 8 + c * 2 + hi], acct, 0, 0, 0);
    }
    const f16x8* Lrow = Lxh + (size_t)(n0 + mrow) * 4;
#pragma unroll
    for (int c = 2; c < 4; ++c) {
        f16x8 a = Lrow[(c - 2) * 2 + hi];
        accz = __builtin_amdgcn_mfma_f32_32x32x16_f16(a, BzT[mrow * 8 + c * 2 + hi], accz, 0, 0, 0);
        acct = __builtin_amdgcn_mfma_f32_32x32x16_f16(a, BhT[mrow * 8 + c * 2 + hi], acct, 0, 0, 0);
    }
    float bz = b_xz[mrow] + b_hz[mrow];
    float bh = b_xh[mrow] + b_hh[mrow];
#pragma unroll
    for (int j = 0; j < 16; ++j) {
        float z = accz[j] + bz, t = acct[j] + bh;
        float Z = 1.0f / (1.0f + expf(-z));
        float H = (1.0f - Z) * tanhf(t);
        int r = (j & 3) + 8 * (j >> 2) + 4 * hi;
        Hw[r * 40 + mrow] = h16(H);          // H^T staging (row=node, col=f)
    }
    f32x16 acch = {};
#pragma unroll
    for (int c = 0; c < 2; ++c) {
        f16x8 hfrag = *reinterpret_cast<const f16x8*>(&Hw[mrow * 40 + c * 16 + hi * 8]);
        acch = __builtin_amdgcn_mfma_f32_32x32x16_f16(hfrag, WgT[mrow * 4 + c * 2 + hi], acch, 0, 0, 0);
    }
#pragma unroll
    for (int j = 0; j < 16; ++j) {
        int r = (j & 3) + 8 * (j >> 2) + 4 * hi;
        int node = n0 + r;
        unsigned short hv = h16(disg[node] * acch[j]);
        if (mrow < 16) hws_lo[node * 16 + mrow] = hv;
        else           hws_hi[node * 16 + (mrow - 16)] = hv;
    }
}

// ---------------------------------------------------------------------------
// K_gath_h: XCD-split single launch + FUSED GCN epilogue.
// acc_f = disg*(sum_e hws[src] + hws[node]); relu/W_lin dot distributes over
// feature halves -> per-node partial scalar pf[half][node].
// ---------------------------------------------------------------------------
__global__ __launch_bounds__(256) void k_gath_h(const uint2* __restrict__ hws_lo2,
                                                const uint2* __restrict__ hws_hi2,
                                                const int* __restrict__ csr_s,
                                                const int* __restrict__ start,
                                                const int* __restrict__ cd,
                                                const float* __restrict__ disg,
                                                const float* __restrict__ b_gcn,
                                                const float* __restrict__ W_lin,
                                                float* __restrict__ pf) {
    int tid = threadIdx.x, blk = blockIdx.x;
    int half = (blk >> 2) & 1;
    int oct = (blk >> 3) * 4 + (blk & 3);
    int node = oct * 8 + (tid >> 5);
    int lane = tid & 31, grp = lane >> 2, c4 = lane & 3;
    int st = start[node], cn = cd[node];
    const uint2* tab = half ? hws_hi2 : hws_lo2;

    float a0 = 0.f, a1 = 0.f, a2 = 0.f, a3 = 0.f;
    for (int j = 0; j < cn; j += 16) {
        int e0 = j + grp, e1 = j + 8 + grp;
        int c0 = e0 < cn ? e0 : cn - 1;  float m0 = e0 < cn ? 1.0f : 0.0f;
        int c1 = e1 < cn ? e1 : cn - 1;  float m1 = e1 < cn ? 1.0f : 0.0f;
        int s0 = csr_s[st + c0], s1 = csr_s[st + c1];
        uint2 v0 = tab[s0 * 4 + c4];
        uint2 v1 = tab[s1 * 4 + c4];
        a0 = fmaf(m0, h16lo(v0.x), a0);  a1 = fmaf(m0, h16hi(v0.x), a1);
        a2 = fmaf(m0, h16lo(v0.y), a2);  a3 = fmaf(m0, h16hi(v0.y), a3);
        a0 = fmaf(m1, h16lo(v1.x), a0);  a1 = fmaf(m1, h16hi(v1.x), a1);
        a2 = fmaf(m1, h16lo(v1.y), a2);  a3 = fmaf(m1, h16hi(v1.y), a3);
    }
#pragma unroll
    for (int off = 4; off < 32; off <<= 1) {
        a0 += __shfl_xor(a0, off, 32);
        a1 += __shfl_xor(a1, off, 32);
        a2 += __shfl_xor(a2, off, 32);
        a3 += __shfl_xor(a3, off, 32);
    }
    // self row (pre-scaled by disg[src]=disg[node]) — same cols for all lanes
    uint2 sv = tab[node * 4 + c4];
    float dg = disg[node];
    int f0 = half * 16 + 4 * c4;
    float h0 = dg * (a0 + h16lo(sv.x)) + b_gcn[f0];
    float h1 = dg * (a1 + h16hi(sv.x)) + b_gcn[f0 + 1];
    float h2v = dg * (a2 + h16lo(sv.y)) + b_gcn[f0 + 2];
    float h3 = dg * (a3 + h16hi(sv.y)) + b_gcn[f0 + 3];
    float p = fmaxf(h0, 0.0f) * W_lin[f0]
            + fmaxf(h1, 0.0f) * W_lin[f0 + 1]
            + fmaxf(h2v, 0.0f) * W_lin[f0 + 2]
            + fmaxf(h3, 0.0f) * W_lin[f0 + 3];
    p += __shfl_xor(p, 1, 32);
    p += __shfl_xor(p, 2, 32);
    if (lane == 0) pf[half * NN + node] = p;
}

// ---------------------------------------------------------------------------
// K_fin2: out[node] = pf_lo + pf_hi + b_lin
// ---------------------------------------------------------------------------
__global__ __launch_bounds__(256) void k_fin2(const float* __restrict__ pf,
                                              const float* __restrict__ b_lin,
                                              float* __restrict__ out) {
    int i = blockIdx.x * 256 + threadIdx.x;
    if (i < NN) out[i] = pf[i] + pf[NN + i] + b_lin[0];
}

extern "C" void kernel_launch(void* const* d_in, const int* in_sizes, int n_in,
                              void* d_out, int out_size, void* d_ws, size_t ws_size,
                              hipStream_t stream) {
    const float* x     = (const float*)d_in[0];
    const int*   ei    = (const int*)d_in[1];
    const int*   src   = ei;
    const int*   dst   = ei + NE;
    const float* W_xz  = (const float*)d_in[2];
    const float* b_xz  = (const float*)d_in[3];
    const float* b_hz  = (const float*)d_in[5];
    // W_xr/b_xr/W_hr/b_hr (d_in[6..9]) are dead: R only multiplies H0 == 0.
    const float* W_xh  = (const float*)d_in[10];
    const float* b_xh  = (const float*)d_in[11];
    const float* b_hh  = (const float*)d_in[13];
    const float* W_gcn = (const float*)d_in[14];
    const float* b_gcn = (const float*)d_in[15];
    const float* W_lin = (const float*)d_in[16];
    const float* b_lin = (const float*)d_in[17];
    float* out = (float*)d_out;

    // Workspace (4B words), ~37.6 MB.  Only cur_d/cur_s need zeroing (3.1KB).
    // Aliases: xs_lo/xs_hi overlay bkd arena (dead after k_p2); 16N <= NB*ASTR.
    // Sizes audited (R9 lesson): BzT/BhT = 2048 ushorts = 1024 words each,
    // WgT = 1024 ushorts = 512 words.
    int* w = (int*)d_ws;
    int* cur_d = w;                       w += 392;
    int* cur_s = w;                       w += 392;
    int* cd    = w;                       w += NN;
    int* start = w;                       w += NN;
    float* dis  = (float*)w;              w += NN;
    float* disg = (float*)w;              w += NN;
    float* pf   = (float*)w;              w += 2 * NN;
    unsigned short* hws_lo = (unsigned short*)w;  w += 8 * NN;   // 16 fp16/node
    unsigned short* hws_hi = (unsigned short*)w;  w += 8 * NN;
    unsigned* Lxh = (unsigned*)w;         w += 16 * NN;          // 32 fp16/node
    unsigned* bkd = (unsigned*)w;         w += NB * ASTR;        // 3,203,072
    unsigned char* bks = (unsigned char*)w; w += (NB * ASTR) / 4;
    int* csr_s = w;                       w += NE;
    unsigned short* BzT = (unsigned short*)w; w += 1024;         // 32f x 64k
    unsigned short* BhT = (unsigned short*)w; w += 1024;
    unsigned short* WgT = (unsigned short*)w; w += 512;          // 32f x 32k
    unsigned short* xs_lo = (unsigned short*)bkd;                // alias
    unsigned short* xs_hi = (unsigned short*)(bkd + 8 * NN);

    hipMemsetAsync(cur_d, 0, 784 * sizeof(int), stream);

    k_bucket <<<NBLK, BT, 0, stream>>>(src, dst, cur_d, cur_s, bkd, bks);
    k_p2     <<<NB, 256, 0, stream>>>(bkd, bks, cur_d, cur_s,
                                      cd, start, csr_s, dis, disg);
    k_cvt    <<<(NN * 32) / 256 + 1, 256, 0, stream>>>(x, dis, xs_lo, xs_hi,
                                      W_xz, W_xh, W_gcn, BzT, BhT, WgT);
    k_gath_lx<<<25000, 256, 0, stream>>>((const uint2*)xs_lo, (const uint2*)xs_hi,
                                         csr_s, start, cd, dis, Lxh);
    k_dmm    <<<782, 256, 0, stream>>>(x, (const f16x8*)Lxh, (const f16x8*)BzT,
                                       (const f16x8*)BhT, (const f16x8*)WgT,
                                       b_xz, b_hz, b_xh, b_hh, disg,
                                       hws_lo, hws_hi);
    k_gath_h <<<25000, 256, 0, stream>>>((const uint2*)hws_lo, (const uint2*)hws_hi,
                                         csr_s, start, cd, disg,
                                         b_gcn, W_lin, pf);
    k_fin2   <<<(NN + 255) / 256, 256, 0, stream>>>(pf, b_lin, out);
}

// Round 13
// 145.744 us; speedup vs baseline: 1.8931x; 1.0445x over previous
//
#include <hip/hip_runtime.h>
#include <hip/hip_fp16.h>

#define NN 100000
#define NE 1600000
#define NB 391        // node buckets: node >> 8 (256 nodes/bucket, last=160)
#define NBLK 391      // edge chunks of CHUNK
#define CHUNK 4096
#define BT 1024       // k_bucket block size
#define PT 1024       // k_p2 block size
#define ASTR 8192     // arena stride/bucket; counts ~Bin(1.6M,256/1e5):
                      // mean 4096, sd 64 -> 8192 is +64 sd, cannot overflow

// ---- fp16 helpers ----------------------------------------------------------
__device__ __forceinline__ float h16lo(unsigned u) {
    return __half2float(__ushort_as_half((unsigned short)(u & 0xffffu)));
}
__device__ __forceinline__ float h16hi(unsigned u) {
    return __half2float(__ushort_as_half((unsigned short)(u >> 16)));
}
__device__ __forceinline__ unsigned short h16(float f) {
    return __half_as_ushort(__float2half(f));
}
__device__ __forceinline__ unsigned pack2h(float a, float b) {
    return (unsigned)h16(a) | ((unsigned)h16(b) << 16);
}

using f16x8  = __attribute__((ext_vector_type(8)))  _Float16;
using f32x16 = __attribute__((ext_vector_type(16))) float;

// ---------------------------------------------------------------------------
// B1: fused count + LDS counting-sort + coalesced arena write (R12, passing).
// ---------------------------------------------------------------------------
__global__ __launch_bounds__(BT) void k_bucket(
        const int* __restrict__ src, const int* __restrict__ dst,
        int* __restrict__ cur_d, int* __restrict__ cur_s,
        unsigned* __restrict__ bkd, unsigned char* __restrict__ bks) {
    __shared__ int hd[NB], hs[NB];            // hist, then LDS cursors
    __shared__ int bd[NB], bs[NB];            // claimed global bases
    __shared__ int od[NB], os[NB];            // local exclusive offsets
    __shared__ int t0[512], t1[512];          // scan temps
    __shared__ unsigned       sortd[CHUNK];   // dst-sorted packed entries
    __shared__ unsigned short sbkt [CHUNK];   // bucket id per entry (dst)
    __shared__ unsigned char  sorts[CHUNK];   // src-sorted bytes
    __shared__ unsigned short sbkts[CHUNK];   // bucket id per entry (src)

    int tid = threadIdx.x, blk = blockIdx.x;
    if (tid < NB) { hd[tid] = 0; hs[tid] = 0; }
    __syncthreads();

    int e0 = blk * CHUNK, ee = min(e0 + CHUNK, NE);
    int sv[4], dv[4]; bool va[4];
#pragma unroll
    for (int u = 0; u < 4; ++u) {
        int e = e0 + u * BT + tid;
        va[u] = e < ee;
        if (va[u]) {
            sv[u] = src[e]; dv[u] = dst[e];
            atomicAdd(&hd[dv[u] >> 8], 1);
            atomicAdd(&hs[sv[u] >> 8], 1);
        }
    }
    __syncthreads();

    if (tid < 512) {
        t0[tid] = tid < NB ? hd[tid] : 0;
        t1[tid] = tid < NB ? hs[tid] : 0;
    }
    __syncthreads();
    for (int off = 1; off < 512; off <<= 1) {
        int a = 0, b = 0;
        if (tid < 512 && tid >= off) { a = t0[tid - off]; b = t1[tid - off]; }
        __syncthreads();
        if (tid < 512) { t0[tid] += a; t1[tid] += b; }
        __syncthreads();
    }
    if (tid < NB) {
        int c = hd[tid], c2 = hs[tid];
        od[tid] = t0[tid] - c;
        os[tid] = t1[tid] - c2;
        bd[tid] = c  ? atomicAdd(&cur_d[tid], c)  : 0;
        bs[tid] = c2 ? atomicAdd(&cur_s[tid], c2) : 0;
        hd[tid] = od[tid];            // reuse as LDS cursors
        hs[tid] = os[tid];
    }
    __syncthreads();

#pragma unroll
    for (int u = 0; u < 4; ++u) if (va[u]) {
        int bu = dv[u] >> 8;
        int p = atomicAdd(&hd[bu], 1);
        sortd[p] = ((unsigned)(dv[u] & 255) << 17) | (unsigned)sv[u];
        sbkt[p]  = (unsigned short)bu;
        int bv = sv[u] >> 8;
        int q = atomicAdd(&hs[bv], 1);
        sorts[q] = (unsigned char)(sv[u] & 255);
        sbkts[q] = (unsigned short)bv;
    }
    __syncthreads();

    int n = ee - e0;
    for (int i = tid; i < n; i += BT) {
        int b1 = sbkt[i];
        bkd[b1 * ASTR + bd[b1] + (i - od[b1])] = sortd[i];
        int b2 = sbkts[i];
        bks[b2 * ASTR + bs[b2] + (i - os[b2])] = sorts[i];
    }
}

// ---------------------------------------------------------------------------
// B2 (FUSED scanb+p2d+p2s+norm), now 1024 threads (was 256 -> 12% occupancy).
// Histogram/scatter loops stride PT; 256-wide scans on first 256 lanes with
// full-block barriers.
// ---------------------------------------------------------------------------
__global__ __launch_bounds__(PT) void k_p2(const unsigned* __restrict__ bkd,
                                           const unsigned char* __restrict__ bks,
                                           const int* __restrict__ cur_d,
                                           const int* __restrict__ cur_s,
                                           int* __restrict__ cd,
                                           int* __restrict__ start,
                                           int* __restrict__ csr_s,
                                           float* __restrict__ dis,
                                           float* __restrict__ disg) {
    __shared__ int hist[256], scn[256], hsA[256];
    __shared__ int red[PT];
    int b = blockIdx.x, tid = threadIdx.x;
    if (tid < 256) { hist[tid] = 0; hsA[tid] = 0; }
    // csr base for this bucket = sum_{i<b} cur_d[i]
    int acc = 0;
    for (int i = tid; i < b; i += PT) acc += cur_d[i];
    red[tid] = acc;
    __syncthreads();
    for (int off = PT / 2; off > 0; off >>= 1) {
        if (tid < off) red[tid] += red[tid + off];
        __syncthreads();
    }
    int cb = red[0];

    int eb = b * ASTR, ee = eb + cur_d[b];
    for (int e = eb + tid; e < ee; e += PT)
        atomicAdd(&hist[bkd[e] >> 17], 1);
    int sb = b * ASTR, se = sb + cur_s[b];
    for (int e = sb + tid; e < se; e += PT)
        atomicAdd(&hsA[bks[e]], 1);
    __syncthreads();
    int c = (tid < 256) ? hist[tid] : 0;
    if (tid < 256) scn[tid] = c;
    __syncthreads();
    for (int off = 1; off < 256; off <<= 1) {
        int t = (tid < 256 && tid >= off) ? scn[tid - off] : 0;
        __syncthreads();
        if (tid < 256) scn[tid] += t;
        __syncthreads();
    }
    if (tid < 256) {
        int excl = scn[tid] - c;
        int node = (b << 8) + tid;
        if (node < NN) {
            cd[node] = c;
            start[node] = cb + excl;
            int oc = hsA[tid];
            dis[node]  = oc > 0 ? rsqrtf((float)oc) : 0.0f;
            disg[node] = rsqrtf((float)c + 1.0f);
        }
    }
    __syncthreads();              // all hsA reads done
    if (tid < 256) hsA[tid] = cb + scn[tid] - c;   // reuse as csr cursor
    __syncthreads();
    for (int e = eb + tid; e < ee; e += PT) {
        unsigned pk = bkd[e];
        int p = atomicAdd(&hsA[pk >> 17], 1);
        csr_s[p] = (int)(pk & 0x1FFFFu);
    }
}

// ---------------------------------------------------------------------------
// K_cvt (+wcvt folded in the extra block): fp16 gather tables (R12, passing).
// ---------------------------------------------------------------------------
__global__ __launch_bounds__(256) void k_cvt(const float* __restrict__ x,
                                             const float* __restrict__ dis,
                                             unsigned short* __restrict__ xs_lo,
                                             unsigned short* __restrict__ xs_hi,
                                             const float* __restrict__ W_xz,
                                             const float* __restrict__ W_xh,
                                             const float* __restrict__ W_gcn,
                                             unsigned short* __restrict__ BzT,
                                             unsigned short* __restrict__ BhT,
                                             unsigned short* __restrict__ WgT) {
    int tid = threadIdx.x;
    int i = blockIdx.x * 256 + tid;
    if (i < NN * 32) {
        int node = i >> 5, f = i & 31;
        unsigned short hsv = h16(x[i] * dis[node]);
        if (f < 16) xs_lo[node * 16 + f] = hsv;
        else        xs_hi[node * 16 + (f - 16)] = hsv;
    } else if (blockIdx.x == (NN * 32) / 256) {
        for (int idx = tid; idx < 2048; idx += 256) {
            int f = idx >> 6, k = idx & 63;
            float vz = (k < 32) ? W_xz[k * 32 + f] : W_xz[1024 + (k - 32) * 32 + f];
            float vh = (k < 32) ? W_xh[k * 32 + f] : W_xh[1024 + (k - 32) * 32 + f];
            BzT[idx] = h16(vz);
            BhT[idx] = h16(vh);
        }
        for (int idx = tid; idx < 1024; idx += 256) {
            int f = idx >> 5, k = idx & 31;
            WgT[idx] = h16(W_gcn[k * 32 + f]);
        }
    }
}

// ---------------------------------------------------------------------------
// K_gath_lx: XCD-split single launch, uint4 (16B) gathers — 2 lanes/edge,
// 32 edges (rows) in flight per 32-lane group, half the vmem instructions of
// the uint2 version.  Writes Lx half-row (fp16) pre-multiplied by -dis[dst].
// ---------------------------------------------------------------------------
__global__ __launch_bounds__(256) void k_gath_lx(const uint4* __restrict__ xs_lo4,
                                                 const uint4* __restrict__ xs_hi4,
                                                 const int* __restrict__ csr_s,
                                                 const int* __restrict__ start,
                                                 const int* __restrict__ cd,
                                                 const float* __restrict__ dis,
                                                 unsigned* __restrict__ Lxh) {
    int tid = threadIdx.x, blk = blockIdx.x;
    int half = (blk >> 2) & 1;
    int oct = (blk >> 3) * 4 + (blk & 3);          // [0, 12500)
    int node = oct * 8 + (tid >> 5);
    int lane = tid & 31, eoff = lane >> 1, cc = lane & 1;
    int st = start[node], cn = cd[node];
    const uint4* tab = half ? xs_hi4 : xs_lo4;

    float a0 = 0.f, a1 = 0.f, a2 = 0.f, a3 = 0.f;
    float a4 = 0.f, a5 = 0.f, a6 = 0.f, a7 = 0.f;
    for (int j = 0; j < cn; j += 32) {
        int e0 = j + eoff, e1 = j + 16 + eoff;
        int c0 = e0 < cn ? e0 : cn - 1;  float m0 = e0 < cn ? 1.0f : 0.0f;
        int c1 = e1 < cn ? e1 : cn - 1;  float m1 = e1 < cn ? 1.0f : 0.0f;
        int s0 = csr_s[st + c0], s1 = csr_s[st + c1];
        uint4 v0 = tab[s0 * 2 + cc];
        uint4 v1 = tab[s1 * 2 + cc];
        a0 = fmaf(m0, h16lo(v0.x), a0);  a1 = fmaf(m0, h16hi(v0.x), a1);
        a2 = fmaf(m0, h16lo(v0.y), a2);  a3 = fmaf(m0, h16hi(v0.y), a3);
        a4 = fmaf(m0, h16lo(v0.z), a4);  a5 = fmaf(m0, h16hi(v0.z), a5);
        a6 = fmaf(m0, h16lo(v0.w), a6);  a7 = fmaf(m0, h16hi(v0.w), a7);
        a0 = fmaf(m1, h16lo(v1.x), a0);  a1 = fmaf(m1, h16hi(v1.x), a1);
        a2 = fmaf(m1, h16lo(v1.y), a2);  a3 = fmaf(m1, h16hi(v1.y), a3);
        a4 = fmaf(m1, h16lo(v1.z), a4);  a5 = fmaf(m1, h16hi(v1.z), a5);
        a6 = fmaf(m1, h16lo(v1.w), a6);  a7 = fmaf(m1, h16hi(v1.w), a7);
    }
    // parity-preserving butterfly: even lanes sum feats f0..f0+7, odd f0+8..15
#pragma unroll
    for (int off = 2; off < 32; off <<= 1) {
        a0 += __shfl_xor(a0, off, 32);  a1 += __shfl_xor(a1, off, 32);
        a2 += __shfl_xor(a2, off, 32);  a3 += __shfl_xor(a3, off, 32);
        a4 += __shfl_xor(a4, off, 32);  a5 += __shfl_xor(a5, off, 32);
        a6 += __shfl_xor(a6, off, 32);  a7 += __shfl_xor(a7, off, 32);
    }
    if (lane < 2) {      // cc == lane; features half*16 + cc*8 + 0..7
        float w = -dis[node];
        int base = node * 16 + half * 8 + cc * 4;     // uint units
        Lxh[base]     = pack2h(w * a0, w * a1);
        Lxh[base + 1] = pack2h(w * a2, w * a3);
        Lxh[base + 2] = pack2h(w * a4, w * a5);
        Lxh[base + 3] = pack2h(w * a6, w * a7);
    }
}

// ---------------------------------------------------------------------------
// K_dmm: MFMA dense phase (R12, passing).  Per wave: 32 nodes.
// ---------------------------------------------------------------------------
__global__ __launch_bounds__(256) void k_dmm(
        const float* __restrict__ x,
        const f16x8* __restrict__ Lxh,    // [node*4 + (c-2)*2 + hi]
        const f16x8* __restrict__ BzT,
        const f16x8* __restrict__ BhT,
        const f16x8* __restrict__ WgT,
        const float* __restrict__ b_xz, const float* __restrict__ b_hz,
        const float* __restrict__ b_xh, const float* __restrict__ b_hh,
        const float* __restrict__ disg,
        unsigned short* __restrict__ hws_lo,
        unsigned short* __restrict__ hws_hi) {
    __shared__ unsigned short Hl[4 * 1280];   // per-wave 32 x 40 u16 (80B pad)
    int tid = threadIdx.x;
    int wv = blockIdx.x * 4 + (tid >> 6);
    if (wv > 3124) wv = 3124;                 // dup tail wave: same writes, safe
    int l = tid & 63, mrow = l & 31, hi = l >> 5;
    int n0 = wv * 32;
    unsigned short* Hw = Hl + (tid >> 6) * 1280;

    f32x16 accz = {}, acct = {};
    const float* xrow = x + (size_t)(n0 + mrow) * 32;
#pragma unroll
    for (int c = 0; c < 2; ++c) {
        f16x8 a;
        const float* p = xrow + c * 16 + hi * 8;
#pragma unroll
        for (int e = 0; e < 8; ++e) a[e] = (_Float16)p[e];
        accz = __builtin_amdgcn_mfma_f32_32x32x16_f16(a, BzT[mrow * 8 + c * 2 + hi], accz, 0, 0, 0);
        acct = __builtin_amdgcn_mfma_f32_32x32x16_f16(a, BhT[mrow * 8 + c * 2 + hi], acct, 0, 0, 0);
    }
    const f16x8* Lrow = Lxh + (size_t)(n0 + mrow) * 4;
#pragma unroll
    for (int c = 2; c < 4; ++c) {
        f16x8 a = Lrow[(c - 2) * 2 + hi];
        accz = __builtin_amdgcn_mfma_f32_32x32x16_f16(a, BzT[mrow * 8 + c * 2 + hi], accz, 0, 0, 0);
        acct = __builtin_amdgcn_mfma_f32_32x32x16_f16(a, BhT[mrow * 8 + c * 2 + hi], acct, 0, 0, 0);
    }
    float bz = b_xz[mrow] + b_hz[mrow];
    float bh = b_xh[mrow] + b_hh[mrow];
#pragma unroll
    for (int j = 0; j < 16; ++j) {
        float z = accz[j] + bz, t = acct[j] + bh;
        float Z = 1.0f / (1.0f + expf(-z));
        float H = (1.0f - Z) * tanhf(t);
        int r = (j & 3) + 8 * (j >> 2) + 4 * hi;
        Hw[r * 40 + mrow] = h16(H);          // H^T staging (row=node, col=f)
    }
    f32x16 acch = {};
#pragma unroll
    for (int c = 0; c < 2; ++c) {
        f16x8 hfrag = *reinterpret_cast<const f16x8*>(&Hw[mrow * 40 + c * 16 + hi * 8]);
        acch = __builtin_amdgcn_mfma_f32_32x32x16_f16(hfrag, WgT[mrow * 4 + c * 2 + hi], acch, 0, 0, 0);
    }
#pragma unroll
    for (int j = 0; j < 16; ++j) {
        int r = (j & 3) + 8 * (j >> 2) + 4 * hi;
        int node = n0 + r;
        unsigned short hv = h16(disg[node] * acch[j]);
        if (mrow < 16) hws_lo[node * 16 + mrow] = hv;
        else           hws_hi[node * 16 + (mrow - 16)] = hv;
    }
}

// ---------------------------------------------------------------------------
// K_gath_h: XCD-split uint4 gather + FUSED GCN epilogue.
// ---------------------------------------------------------------------------
__global__ __launch_bounds__(256) void k_gath_h(const uint4* __restrict__ hws_lo4,
                                                const uint4* __restrict__ hws_hi4,
                                                const int* __restrict__ csr_s,
                                                const int* __restrict__ start,
                                                const int* __restrict__ cd,
                                                const float* __restrict__ disg,
                                                const float* __restrict__ b_gcn,
                                                const float* __restrict__ W_lin,
                                                float* __restrict__ pf) {
    int tid = threadIdx.x, blk = blockIdx.x;
    int half = (blk >> 2) & 1;
    int oct = (blk >> 3) * 4 + (blk & 3);
    int node = oct * 8 + (tid >> 5);
    int lane = tid & 31, eoff = lane >> 1, cc = lane & 1;
    int st = start[node], cn = cd[node];
    const uint4* tab = half ? hws_hi4 : hws_lo4;

    float a0 = 0.f, a1 = 0.f, a2 = 0.f, a3 = 0.f;
    float a4 = 0.f, a5 = 0.f, a6 = 0.f, a7 = 0.f;
    for (int j = 0; j < cn; j += 32) {
        int e0 = j + eoff, e1 = j + 16 + eoff;
        int c0 = e0 < cn ? e0 : cn - 1;  float m0 = e0 < cn ? 1.0f : 0.0f;
        int c1 = e1 < cn ? e1 : cn - 1;  float m1 = e1 < cn ? 1.0f : 0.0f;
        int s0 = csr_s[st + c0], s1 = csr_s[st + c1];
        uint4 v0 = tab[s0 * 2 + cc];
        uint4 v1 = tab[s1 * 2 + cc];
        a0 = fmaf(m0, h16lo(v0.x), a0);  a1 = fmaf(m0, h16hi(v0.x), a1);
        a2 = fmaf(m0, h16lo(v0.y), a2);  a3 = fmaf(m0, h16hi(v0.y), a3);
        a4 = fmaf(m0, h16lo(v0.z), a4);  a5 = fmaf(m0, h16hi(v0.z), a5);
        a6 = fmaf(m0, h16lo(v0.w), a6);  a7 = fmaf(m0, h16hi(v0.w), a7);
        a0 = fmaf(m1, h16lo(v1.x), a0);  a1 = fmaf(m1, h16hi(v1.x), a1);
        a2 = fmaf(m1, h16lo(v1.y), a2);  a3 = fmaf(m1, h16hi(v1.y), a3);
        a4 = fmaf(m1, h16lo(v1.z), a4);  a5 = fmaf(m1, h16hi(v1.z), a5);
        a6 = fmaf(m1, h16lo(v1.w), a6);  a7 = fmaf(m1, h16hi(v1.w), a7);
    }
#pragma unroll
    for (int off = 2; off < 32; off <<= 1) {
        a0 += __shfl_xor(a0, off, 32);  a1 += __shfl_xor(a1, off, 32);
        a2 += __shfl_xor(a2, off, 32);  a3 += __shfl_xor(a3, off, 32);
        a4 += __shfl_xor(a4, off, 32);  a5 += __shfl_xor(a5, off, 32);
        a6 += __shfl_xor(a6, off, 32);  a7 += __shfl_xor(a7, off, 32);
    }
    if (lane < 2) {      // cc == lane; features f0 = half*16 + cc*8
        uint4 sv = tab[node * 2 + cc];   // self row (pre-scaled by disg)
        float dg = disg[node];
        int f0 = half * 16 + cc * 8;
        float h0 = dg * (a0 + h16lo(sv.x)) + b_gcn[f0];
        float h1 = dg * (a1 + h16hi(sv.x)) + b_gcn[f0 + 1];
        float h2 = dg * (a2 + h16lo(sv.y)) + b_gcn[f0 + 2];
        float h3 = dg * (a3 + h16hi(sv.y)) + b_gcn[f0 + 3];
        float h4 = dg * (a4 + h16lo(sv.z)) + b_gcn[f0 + 4];
        float h5 = dg * (a5 + h16hi(sv.z)) + b_gcn[f0 + 5];
        float h6 = dg * (a6 + h16lo(sv.w)) + b_gcn[f0 + 6];
        float h7 = dg * (a7 + h16hi(sv.w)) + b_gcn[f0 + 7];
        float p = fmaxf(h0, 0.0f) * W_lin[f0]
                + fmaxf(h1, 0.0f) * W_lin[f0 + 1]
                + fmaxf(h2, 0.0f) * W_lin[f0 + 2]
                + fmaxf(h3, 0.0f) * W_lin[f0 + 3]
                + fmaxf(h4, 0.0f) * W_lin[f0 + 4]
                + fmaxf(h5, 0.0f) * W_lin[f0 + 5]
                + fmaxf(h6, 0.0f) * W_lin[f0 + 6]
                + fmaxf(h7, 0.0f) * W_lin[f0 + 7];
        p += __shfl_xor(p, 1, 32);       // lanes 0,1 both active here
        if (cc == 0) pf[half * NN + node] = p;
    }
}

// ---------------------------------------------------------------------------
// K_fin2: out[node] = pf_lo + pf_hi + b_lin
// ---------------------------------------------------------------------------
__global__ __launch_bounds__(256) void k_fin2(const float* __restrict__ pf,
                                              const float* __restrict__ b_lin,
                                              float* __restrict__ out) {
    int i = blockIdx.x * 256 + threadIdx.x;
    if (i < NN) out[i] = pf[i] + pf[NN + i] + b_lin[0];
}

extern "C" void kernel_launch(void* const* d_in, const int* in_sizes, int n_in,
                              void* d_out, int out_size, void* d_ws, size_t ws_size,
                              hipStream_t stream) {
    const float* x     = (const float*)d_in[0];
    const int*   ei    = (const int*)d_in[1];
    const int*   src   = ei;
    const int*   dst   = ei + NE;
    const float* W_xz  = (const float*)d_in[2];
    const float* b_xz  = (const float*)d_in[3];
    const float* b_hz  = (const float*)d_in[5];
    // W_xr/b_xr/W_hr/b_hr (d_in[6..9]) are dead: R only multiplies H0 == 0.
    const float* W_xh  = (const float*)d_in[10];
    const float* b_xh  = (const float*)d_in[11];
    const float* b_hh  = (const float*)d_in[13];
    const float* W_gcn = (const float*)d_in[14];
    const float* b_gcn = (const float*)d_in[15];
    const float* W_lin = (const float*)d_in[16];
    const float* b_lin = (const float*)d_in[17];
    float* out = (float*)d_out;

    // Workspace (4B words), ~37.6 MB.  Only cur_d/cur_s need zeroing (3.1KB).
    // Aliases: xs_lo/xs_hi overlay bkd arena (dead after k_p2); 16N <= NB*ASTR.
    // All table bases are multiples of 16B (offsets audited for uint4 loads).
    int* w = (int*)d_ws;
    int* cur_d = w;                       w += 392;
    int* cur_s = w;                       w += 392;
    int* cd    = w;                       w += NN;
    int* start = w;                       w += NN;
    float* dis  = (float*)w;              w += NN;
    float* disg = (float*)w;              w += NN;
    float* pf   = (float*)w;              w += 2 * NN;
    unsigned short* hws_lo = (unsigned short*)w;  w += 8 * NN;   // 16 fp16/node
    unsigned short* hws_hi = (unsigned short*)w;  w += 8 * NN;
    unsigned* Lxh = (unsigned*)w;         w += 16 * NN;          // 32 fp16/node
    unsigned* bkd = (unsigned*)w;         w += NB * ASTR;        // 3,203,072
    unsigned char* bks = (unsigned char*)w; w += (NB * ASTR) / 4;
    int* csr_s = w;                       w += NE;
    unsigned short* BzT = (unsigned short*)w; w += 1024;         // 32f x 64k
    unsigned short* BhT = (unsigned short*)w; w += 1024;
    unsigned short* WgT = (unsigned short*)w; w += 512;          // 32f x 32k
    unsigned short* xs_lo = (unsigned short*)bkd;                // alias
    unsigned short* xs_hi = (unsigned short*)(bkd + 8 * NN);

    hipMemsetAsync(cur_d, 0, 784 * sizeof(int), stream);

    k_bucket <<<NBLK, BT, 0, stream>>>(src, dst, cur_d, cur_s, bkd, bks);
    k_p2     <<<NB, PT, 0, stream>>>(bkd, bks, cur_d, cur_s,
                                     cd, start, csr_s, dis, disg);
    k_cvt    <<<(NN * 32) / 256 + 1, 256, 0, stream>>>(x, dis, xs_lo, xs_hi,
                                      W_xz, W_xh, W_gcn, BzT, BhT, WgT);
    k_gath_lx<<<25000, 256, 0, stream>>>((const uint4*)xs_lo, (const uint4*)xs_hi,
                                         csr_s, start, cd, dis, Lxh);
    k_dmm    <<<782, 256, 0, stream>>>(x, (const f16x8*)Lxh, (const f16x8*)BzT,
                                       (const f16x8*)BhT, (const f16x8*)WgT,
                                       b_xz, b_hz, b_xh, b_hh, disg,
                                       hws_lo, hws_hi);
    k_gath_h <<<25000, 256, 0, stream>>>((const uint4*)hws_lo, (const uint4*)hws_hi,
                                         csr_s, start, cd, disg,
                                         b_gcn, W_lin, pf);
    k_fin2   <<<(NN + 255) / 256, 256, 0, stream>>>(pf, b_lin, out);
}

// Round 14
// 125.268 us; speedup vs baseline: 2.2026x; 1.1635x over previous
//
#include <hip/hip_runtime.h>
#include <hip/hip_fp16.h>

#define NN 100000
#define NE 1600000
#define NB 391        // node buckets: node >> 8 (256 nodes/bucket, last=160)
#define NBLK 391      // edge chunks of CHUNK
#define CHUNK 4096
#define BT 1024       // k_bucket block size
#define PT 1024       // k_p2 block size
#define ASTR 8192     // arena stride/bucket; counts ~Bin(1.6M,256/1e5):
                      // mean 4096, sd 64 -> 8192 is +64 sd, cannot overflow

// ---- fp16 helpers ----------------------------------------------------------
__device__ __forceinline__ float h16lo(unsigned u) {
    return __half2float(__ushort_as_half((unsigned short)(u & 0xffffu)));
}
__device__ __forceinline__ float h16hi(unsigned u) {
    return __half2float(__ushort_as_half((unsigned short)(u >> 16)));
}
__device__ __forceinline__ unsigned short h16(float f) {
    return __half_as_ushort(__float2half(f));
}
__device__ __forceinline__ unsigned pack2h(float a, float b) {
    return (unsigned)h16(a) | ((unsigned)h16(b) << 16);
}

using f16x8  = __attribute__((ext_vector_type(8)))  _Float16;
using f32x16 = __attribute__((ext_vector_type(16))) float;

// ---------------------------------------------------------------------------
// B1: fused count + LDS counting-sort + coalesced arena write (R12, passing).
// ---------------------------------------------------------------------------
__global__ __launch_bounds__(BT) void k_bucket(
        const int* __restrict__ src, const int* __restrict__ dst,
        int* __restrict__ cur_d, int* __restrict__ cur_s,
        unsigned* __restrict__ bkd, unsigned char* __restrict__ bks) {
    __shared__ int hd[NB], hs[NB];            // hist, then LDS cursors
    __shared__ int bd[NB], bs[NB];            // claimed global bases
    __shared__ int od[NB], os[NB];            // local exclusive offsets
    __shared__ int t0[512], t1[512];          // scan temps
    __shared__ unsigned       sortd[CHUNK];   // dst-sorted packed entries
    __shared__ unsigned short sbkt [CHUNK];   // bucket id per entry (dst)
    __shared__ unsigned char  sorts[CHUNK];   // src-sorted bytes
    __shared__ unsigned short sbkts[CHUNK];   // bucket id per entry (src)

    int tid = threadIdx.x, blk = blockIdx.x;
    if (tid < NB) { hd[tid] = 0; hs[tid] = 0; }
    __syncthreads();

    int e0 = blk * CHUNK, ee = min(e0 + CHUNK, NE);
    int sv[4], dv[4]; bool va[4];
#pragma unroll
    for (int u = 0; u < 4; ++u) {
        int e = e0 + u * BT + tid;
        va[u] = e < ee;
        if (va[u]) {
            sv[u] = src[e]; dv[u] = dst[e];
            atomicAdd(&hd[dv[u] >> 8], 1);
            atomicAdd(&hs[sv[u] >> 8], 1);
        }
    }
    __syncthreads();

    if (tid < 512) {
        t0[tid] = tid < NB ? hd[tid] : 0;
        t1[tid] = tid < NB ? hs[tid] : 0;
    }
    __syncthreads();
    for (int off = 1; off < 512; off <<= 1) {
        int a = 0, b = 0;
        if (tid < 512 && tid >= off) { a = t0[tid - off]; b = t1[tid - off]; }
        __syncthreads();
        if (tid < 512) { t0[tid] += a; t1[tid] += b; }
        __syncthreads();
    }
    if (tid < NB) {
        int c = hd[tid], c2 = hs[tid];
        od[tid] = t0[tid] - c;
        os[tid] = t1[tid] - c2;
        bd[tid] = c  ? atomicAdd(&cur_d[tid], c)  : 0;
        bs[tid] = c2 ? atomicAdd(&cur_s[tid], c2) : 0;
        hd[tid] = od[tid];            // reuse as LDS cursors
        hs[tid] = os[tid];
    }
    __syncthreads();

#pragma unroll
    for (int u = 0; u < 4; ++u) if (va[u]) {
        int bu = dv[u] >> 8;
        int p = atomicAdd(&hd[bu], 1);
        sortd[p] = ((unsigned)(dv[u] & 255) << 17) | (unsigned)sv[u];
        sbkt[p]  = (unsigned short)bu;
        int bv = sv[u] >> 8;
        int q = atomicAdd(&hs[bv], 1);
        sorts[q] = (unsigned char)(sv[u] & 255);
        sbkts[q] = (unsigned short)bv;
    }
    __syncthreads();

    int n = ee - e0;
    for (int i = tid; i < n; i += BT) {
        int b1 = sbkt[i];
        bkd[b1 * ASTR + bd[b1] + (i - od[b1])] = sortd[i];
        int b2 = sbkts[i];
        bks[b2 * ASTR + bs[b2] + (i - os[b2])] = sorts[i];
    }
}

// ---------------------------------------------------------------------------
// B2 (FUSED scanb+p2d+p2s+norm), 1024 threads (R13, passing).
// ---------------------------------------------------------------------------
__global__ __launch_bounds__(PT) void k_p2(const unsigned* __restrict__ bkd,
                                           const unsigned char* __restrict__ bks,
                                           const int* __restrict__ cur_d,
                                           const int* __restrict__ cur_s,
                                           int* __restrict__ cd,
                                           int* __restrict__ start,
                                           int* __restrict__ csr_s,
                                           float* __restrict__ dis,
                                           float* __restrict__ disg) {
    __shared__ int hist[256], scn[256], hsA[256];
    __shared__ int red[PT];
    int b = blockIdx.x, tid = threadIdx.x;
    if (tid < 256) { hist[tid] = 0; hsA[tid] = 0; }
    int acc = 0;
    for (int i = tid; i < b; i += PT) acc += cur_d[i];
    red[tid] = acc;
    __syncthreads();
    for (int off = PT / 2; off > 0; off >>= 1) {
        if (tid < off) red[tid] += red[tid + off];
        __syncthreads();
    }
    int cb = red[0];

    int eb = b * ASTR, ee = eb + cur_d[b];
    for (int e = eb + tid; e < ee; e += PT)
        atomicAdd(&hist[bkd[e] >> 17], 1);
    int sb = b * ASTR, se = sb + cur_s[b];
    for (int e = sb + tid; e < se; e += PT)
        atomicAdd(&hsA[bks[e]], 1);
    __syncthreads();
    int c = (tid < 256) ? hist[tid] : 0;
    if (tid < 256) scn[tid] = c;
    __syncthreads();
    for (int off = 1; off < 256; off <<= 1) {
        int t = (tid < 256 && tid >= off) ? scn[tid - off] : 0;
        __syncthreads();
        if (tid < 256) scn[tid] += t;
        __syncthreads();
    }
    if (tid < 256) {
        int excl = scn[tid] - c;
        int node = (b << 8) + tid;
        if (node < NN) {
            cd[node] = c;
            start[node] = cb + excl;
            int oc = hsA[tid];
            dis[node]  = oc > 0 ? rsqrtf((float)oc) : 0.0f;
            disg[node] = rsqrtf((float)c + 1.0f);
        }
    }
    __syncthreads();              // all hsA reads done
    if (tid < 256) hsA[tid] = cb + scn[tid] - c;   // reuse as csr cursor
    __syncthreads();
    for (int e = eb + tid; e < ee; e += PT) {
        unsigned pk = bkd[e];
        int p = atomicAdd(&hsA[pk >> 17], 1);
        csr_s[p] = (int)(pk & 0x1FFFFu);
    }
}

// ---------------------------------------------------------------------------
// K_cvt (+wcvt in the extra block): SINGLE merged fp16 table.
//   xs[node][32] = fp16(dis[node]*x[node][:])   (64B rows, linear write)
// ---------------------------------------------------------------------------
__global__ __launch_bounds__(256) void k_cvt(const float* __restrict__ x,
                                             const float* __restrict__ dis,
                                             unsigned short* __restrict__ xs,
                                             const float* __restrict__ W_xz,
                                             const float* __restrict__ W_xh,
                                             const float* __restrict__ W_gcn,
                                             unsigned short* __restrict__ BzT,
                                             unsigned short* __restrict__ BhT,
                                             unsigned short* __restrict__ WgT) {
    int tid = threadIdx.x;
    int i = blockIdx.x * 256 + tid;
    if (i < NN * 32) {
        xs[i] = h16(x[i] * dis[i >> 5]);
    } else if (blockIdx.x == (NN * 32) / 256) {
        for (int idx = tid; idx < 2048; idx += 256) {
            int f = idx >> 6, k = idx & 63;
            float vz = (k < 32) ? W_xz[k * 32 + f] : W_xz[1024 + (k - 32) * 32 + f];
            float vh = (k < 32) ? W_xh[k * 32 + f] : W_xh[1024 + (k - 32) * 32 + f];
            BzT[idx] = h16(vz);
            BhT[idx] = h16(vh);
        }
        for (int idx = tid; idx < 1024; idx += 256) {
            int f = idx >> 5, k = idx & 31;
            WgT[idx] = h16(W_gcn[k * 32 + f]);
        }
    }
}

// ---------------------------------------------------------------------------
// K_gath_lx: MERGED single-pass gather (each edge visited once, 64B row =
// one cache line).  8 lanes/edge (uint2 each = 4 feats), 4 f32 accumulators,
// 2-step butterfly.  Writes full 32-feat Lx row pre-multiplied by -dis[dst].
// ---------------------------------------------------------------------------
__global__ __launch_bounds__(256) void k_gath_lx(const uint2* __restrict__ xs2,
                                                 const int* __restrict__ csr_s,
                                                 const int* __restrict__ start,
                                                 const int* __restrict__ cd,
                                                 const float* __restrict__ dis,
                                                 unsigned* __restrict__ Lxh) {
    int tid = threadIdx.x;
    int node = blockIdx.x * 8 + (tid >> 5);
    int lane = tid & 31, eoff = lane >> 3, c = lane & 7;
    int st = start[node], cn = cd[node];

    float a0 = 0.f, a1 = 0.f, a2 = 0.f, a3 = 0.f;
    for (int j = 0; j < cn; j += 8) {
        int e0 = j + eoff, e1 = j + 4 + eoff;
        int c0 = e0 < cn ? e0 : cn - 1;  float m0 = e0 < cn ? 1.0f : 0.0f;
        int c1 = e1 < cn ? e1 : cn - 1;  float m1 = e1 < cn ? 1.0f : 0.0f;
        int s0 = csr_s[st + c0], s1 = csr_s[st + c1];
        uint2 v0 = xs2[s0 * 8 + c];
        uint2 v1 = xs2[s1 * 8 + c];
        a0 = fmaf(m0, h16lo(v0.x), a0);  a1 = fmaf(m0, h16hi(v0.x), a1);
        a2 = fmaf(m0, h16lo(v0.y), a2);  a3 = fmaf(m0, h16hi(v0.y), a3);
        a0 = fmaf(m1, h16lo(v1.x), a0);  a1 = fmaf(m1, h16hi(v1.x), a1);
        a2 = fmaf(m1, h16lo(v1.y), a2);  a3 = fmaf(m1, h16hi(v1.y), a3);
    }
    // butterfly over the 4 eoff groups (offsets 8, 16)
#pragma unroll
    for (int off = 8; off < 32; off <<= 1) {
        a0 += __shfl_xor(a0, off, 32);  a1 += __shfl_xor(a1, off, 32);
        a2 += __shfl_xor(a2, off, 32);  a3 += __shfl_xor(a3, off, 32);
    }
    if (lane < 8) {      // c == lane; features 4c..4c+3
        float w = -dis[node];
        Lxh[node * 16 + 2 * lane]     = pack2h(w * a0, w * a1);
        Lxh[node * 16 + 2 * lane + 1] = pack2h(w * a2, w * a3);
    }
}

// ---------------------------------------------------------------------------
// K_dmm: MFMA dense phase (R13, passing; hws now a single merged table).
// ---------------------------------------------------------------------------
__global__ __launch_bounds__(256) void k_dmm(
        const float* __restrict__ x,
        const f16x8* __restrict__ Lxh,    // [node*4 + (c-2)*2 + hi]
        const f16x8* __restrict__ BzT,
        const f16x8* __restrict__ BhT,
        const f16x8* __restrict__ WgT,
        const float* __restrict__ b_xz, const float* __restrict__ b_hz,
        const float* __restrict__ b_xh, const float* __restrict__ b_hh,
        const float* __restrict__ disg,
        unsigned short* __restrict__ hws) {
    __shared__ unsigned short Hl[4 * 1280];   // per-wave 32 x 40 u16 (80B pad)
    int tid = threadIdx.x;
    int wv = blockIdx.x * 4 + (tid >> 6);
    if (wv > 3124) wv = 3124;                 // dup tail wave: same writes, safe
    int l = tid & 63, mrow = l & 31, hi = l >> 5;
    int n0 = wv * 32;
    unsigned short* Hw = Hl + (tid >> 6) * 1280;

    f32x16 accz = {}, acct = {};
    const float* xrow = x + (size_t)(n0 + mrow) * 32;
#pragma unroll
    for (int c = 0; c < 2; ++c) {
        f16x8 a;
        const float* p = xrow + c * 16 + hi * 8;
#pragma unroll
        for (int e = 0; e < 8; ++e) a[e] = (_Float16)p[e];
        accz = __builtin_amdgcn_mfma_f32_32x32x16_f16(a, BzT[mrow * 8 + c * 2 + hi], accz, 0, 0, 0);
        acct = __builtin_amdgcn_mfma_f32_32x32x16_f16(a, BhT[mrow * 8 + c * 2 + hi], acct, 0, 0, 0);
    }
    const f16x8* Lrow = Lxh + (size_t)(n0 + mrow) * 4;
#pragma unroll
    for (int c = 2; c < 4; ++c) {
        f16x8 a = Lrow[(c - 2) * 2 + hi];
        accz = __builtin_amdgcn_mfma_f32_32x32x16_f16(a, BzT[mrow * 8 + c * 2 + hi], accz, 0, 0, 0);
        acct = __builtin_amdgcn_mfma_f32_32x32x16_f16(a, BhT[mrow * 8 + c * 2 + hi], acct, 0, 0, 0);
    }
    float bz = b_xz[mrow] + b_hz[mrow];
    float bh = b_xh[mrow] + b_hh[mrow];
#pragma unroll
    for (int j = 0; j < 16; ++j) {
        float z = accz[j] + bz, t = acct[j] + bh;
        float Z = 1.0f / (1.0f + expf(-z));
        float H = (1.0f - Z) * tanhf(t);
        int r = (j & 3) + 8 * (j >> 2) + 4 * hi;
        Hw[r * 40 + mrow] = h16(H);          // H^T staging (row=node, col=f)
    }
    f32x16 acch = {};
#pragma unroll
    for (int c = 0; c < 2; ++c) {
        f16x8 hfrag = *reinterpret_cast<const f16x8*>(&Hw[mrow * 40 + c * 16 + hi * 8]);
        acch = __builtin_amdgcn_mfma_f32_32x32x16_f16(hfrag, WgT[mrow * 4 + c * 2 + hi], acch, 0, 0, 0);
    }
#pragma unroll
    for (int j = 0; j < 16; ++j) {
        int r = (j & 3) + 8 * (j >> 2) + 4 * hi;
        int node = n0 + r;
        hws[node * 32 + mrow] = h16(disg[node] * acch[j]);
    }
}

// ---------------------------------------------------------------------------
// K_gath_h: MERGED single-pass gather + FULL fused epilogue.
//   h_f = disg*(sum_e hws[src] + hws[node]) + b_gcn
//   out[node] = sum_f relu(h_f)*W_lin[f] + b_lin   (all in-kernel)
// ---------------------------------------------------------------------------
__global__ __launch_bounds__(256) void k_gath_h(const uint2* __restrict__ hws2,
                                                const int* __restrict__ csr_s,
                                                const int* __restrict__ start,
                                                const int* __restrict__ cd,
                                                const float* __restrict__ disg,
                                                const float* __restrict__ b_gcn,
                                                const float* __restrict__ W_lin,
                                                const float* __restrict__ b_lin,
                                                float* __restrict__ out) {
    int tid = threadIdx.x;
    int node = blockIdx.x * 8 + (tid >> 5);
    int lane = tid & 31, eoff = lane >> 3, c = lane & 7;
    int st = start[node], cn = cd[node];

    float a0 = 0.f, a1 = 0.f, a2 = 0.f, a3 = 0.f;
    for (int j = 0; j < cn; j += 8) {
        int e0 = j + eoff, e1 = j + 4 + eoff;
        int c0 = e0 < cn ? e0 : cn - 1;  float m0 = e0 < cn ? 1.0f : 0.0f;
        int c1 = e1 < cn ? e1 : cn - 1;  float m1 = e1 < cn ? 1.0f : 0.0f;
        int s0 = csr_s[st + c0], s1 = csr_s[st + c1];
        uint2 v0 = hws2[s0 * 8 + c];
        uint2 v1 = hws2[s1 * 8 + c];
        a0 = fmaf(m0, h16lo(v0.x), a0);  a1 = fmaf(m0, h16hi(v0.x), a1);
        a2 = fmaf(m0, h16lo(v0.y), a2);  a3 = fmaf(m0, h16hi(v0.y), a3);
        a0 = fmaf(m1, h16lo(v1.x), a0);  a1 = fmaf(m1, h16hi(v1.x), a1);
        a2 = fmaf(m1, h16lo(v1.y), a2);  a3 = fmaf(m1, h16hi(v1.y), a3);
    }
#pragma unroll
    for (int off = 8; off < 32; off <<= 1) {
        a0 += __shfl_xor(a0, off, 32);  a1 += __shfl_xor(a1, off, 32);
        a2 += __shfl_xor(a2, off, 32);  a3 += __shfl_xor(a3, off, 32);
    }
    float p = 0.0f;
    if (lane < 8) {      // c == lane; features f0 = 4c
        uint2 sv = hws2[node * 8 + lane];   // self row (pre-scaled by disg)
        float dg = disg[node];
        int f0 = 4 * lane;
        float h0 = dg * (a0 + h16lo(sv.x)) + b_gcn[f0];
        float h1 = dg * (a1 + h16hi(sv.x)) + b_gcn[f0 + 1];
        float h2 = dg * (a2 + h16lo(sv.y)) + b_gcn[f0 + 2];
        float h3 = dg * (a3 + h16hi(sv.y)) + b_gcn[f0 + 3];
        p = fmaxf(h0, 0.0f) * W_lin[f0]
          + fmaxf(h1, 0.0f) * W_lin[f0 + 1]
          + fmaxf(h2, 0.0f) * W_lin[f0 + 2]
          + fmaxf(h3, 0.0f) * W_lin[f0 + 3];
    }
    p += __shfl_xor(p, 1, 32);
    p += __shfl_xor(p, 2, 32);
    p += __shfl_xor(p, 4, 32);
    if (lane == 0) out[node] = p + b_lin[0];
}

extern "C" void kernel_launch(void* const* d_in, const int* in_sizes, int n_in,
                              void* d_out, int out_size, void* d_ws, size_t ws_size,
                              hipStream_t stream) {
    const float* x     = (const float*)d_in[0];
    const int*   ei    = (const int*)d_in[1];
    const int*   src   = ei;
    const int*   dst   = ei + NE;
    const float* W_xz  = (const float*)d_in[2];
    const float* b_xz  = (const float*)d_in[3];
    const float* b_hz  = (const float*)d_in[5];
    // W_xr/b_xr/W_hr/b_hr (d_in[6..9]) are dead: R only multiplies H0 == 0.
    const float* W_xh  = (const float*)d_in[10];
    const float* b_xh  = (const float*)d_in[11];
    const float* b_hh  = (const float*)d_in[13];
    const float* W_gcn = (const float*)d_in[14];
    const float* b_gcn = (const float*)d_in[15];
    const float* W_lin = (const float*)d_in[16];
    const float* b_lin = (const float*)d_in[17];
    float* out = (float*)d_out;

    // Workspace (4B words), ~36.8 MB.  Only cur_d/cur_s need zeroing (3.1KB).
    // Aliases: xs (16N words) overlays bkd arena (dead after k_p2), 16N<=NB*ASTR.
    // Alignment audit: hws @400,784 (16B ok), Lxh @2,000,784 (/4 ok),
    // bkd/xs @3,600,784 (/4 ok), BzT tail (/4 ok).  Sizes: BzT/BhT = 1024
    // words (2048 ushorts), WgT = 512 words (R9 lesson).
    int* w = (int*)d_ws;
    int* cur_d = w;                       w += 392;
    int* cur_s = w;                       w += 392;
    int* cd    = w;                       w += NN;
    int* start = w;                       w += NN;
    float* dis  = (float*)w;              w += NN;
    float* disg = (float*)w;              w += NN;
    unsigned short* hws = (unsigned short*)w;  w += 16 * NN;    // 32 fp16/node
    unsigned* Lxh = (unsigned*)w;         w += 16 * NN;         // 32 fp16/node
    unsigned* bkd = (unsigned*)w;         w += NB * ASTR;       // 3,203,072
    unsigned char* bks = (unsigned char*)w; w += (NB * ASTR) / 4;
    int* csr_s = w;                       w += NE;
    unsigned short* BzT = (unsigned short*)w; w += 1024;        // 32f x 64k
    unsigned short* BhT = (unsigned short*)w; w += 1024;
    unsigned short* WgT = (unsigned short*)w; w += 512;         // 32f x 32k
    unsigned short* xs = (unsigned short*)bkd;                  // alias

    hipMemsetAsync(cur_d, 0, 784 * sizeof(int), stream);

    k_bucket <<<NBLK, BT, 0, stream>>>(src, dst, cur_d, cur_s, bkd, bks);
    k_p2     <<<NB, PT, 0, stream>>>(bkd, bks, cur_d, cur_s,
                                     cd, start, csr_s, dis, disg);
    k_cvt    <<<(NN * 32) / 256 + 1, 256, 0, stream>>>(x, dis, xs,
                                      W_xz, W_xh, W_gcn, BzT, BhT, WgT);
    k_gath_lx<<<NN / 8, 256, 0, stream>>>((const uint2*)xs, csr_s, start, cd,
                                          dis, Lxh);
    k_dmm    <<<782, 256, 0, stream>>>(x, (const f16x8*)Lxh, (const f16x8*)BzT,
                                       (const f16x8*)BhT, (const f16x8*)WgT,
                                       b_xz, b_hz, b_xh, b_hh, disg, hws);
    k_gath_h <<<NN / 8, 256, 0, stream>>>((const uint2*)hws, csr_s, start, cd,
                                          disg, b_gcn, W_lin, b_lin, out);
}